// Round 5
// baseline (1004.226 us; speedup 1.0000x reference)
//
#include <hip/hip_runtime.h>
#include <math.h>

// ---------------------------------------------------------------------------
// CogKR pipeline, R8:
//  - score_mfma_k v5: 128 edges/block, launch_bounds(256,4) (<=128 VGPR,
//    4 blocks/CU), 4 col-passes acc[8][1], A staged via global_load_lds into
//    the proven [kt][row][32] XOR-swizzled layout (pre-swizzled source).
//  - gemm16pw_k for step 2: 64x256 block (single N-tile -> A read once),
//    gload_lds B double-buffer, reg-staged fp32->bf16 A with stride-36 LDS.
//  - rest unchanged from R7 (CSR-permuted attrs, all-bf16 GRU chain,
//    head-sorted alpha).
// ---------------------------------------------------------------------------

#define ACT_NONE 0
#define ACT_LRELU 1

typedef __attribute__((ext_vector_type(8))) short short8;
typedef __attribute__((ext_vector_type(4))) float floatx4;

__device__ __forceinline__ ushort f2b(float x) {
    union { float f; unsigned u; } v; v.f = x;
    return (ushort)((v.u + 0x7fffu + ((v.u >> 16) & 1u)) >> 16);
}
__device__ __forceinline__ float b2f(ushort b) {
    union { unsigned u; float f; } v; v.u = ((unsigned)b) << 16;
    return v.f;
}
__device__ __forceinline__ void gload16(const ushort* g, ushort* l) {
    __builtin_amdgcn_global_load_lds(
        (const __attribute__((address_space(1))) void*)g,
        (__attribute__((address_space(3))) void*)l, 16, 0, 0);
}

// ---------------- small fp32 tiled GEMM (relation tables only) ----------------
__global__ __launch_bounds__(256) void gemm_k(
    const float* __restrict__ A, const float* __restrict__ B,
    const float* __restrict__ bias, float* __restrict__ C,
    int M, int N, int K, const int* __restrict__ a_idx, int act)
{
    __shared__ float As[16][68];
    __shared__ float Bs[16][68];
    const int tid = threadIdx.x;
    const int tx = tid & 15, ty = tid >> 4;
    const int m0 = blockIdx.x * 64, n0 = blockIdx.y * 64;
    float acc[4][4] = {};
    const int ar  = tid >> 2;
    const int ac4 = (tid & 3) * 4;
    const int brow = tid >> 4;
    const int bc4  = (tid & 15) * 4;
    const int gm = m0 + ar;
    const float* Arow = nullptr;
    if (gm < M) {
        int r = a_idx ? a_idx[gm] : gm;
        Arow = A + (size_t)r * K;
    }
    for (int k0 = 0; k0 < K; k0 += 16) {
        float4 av = make_float4(0.f, 0.f, 0.f, 0.f);
        if (Arow) av = *(const float4*)(Arow + k0 + ac4);
        As[ac4 + 0][ar] = av.x;
        As[ac4 + 1][ar] = av.y;
        As[ac4 + 2][ar] = av.z;
        As[ac4 + 3][ar] = av.w;
        float4 bv = *(const float4*)(B + (size_t)(k0 + brow) * N + n0 + bc4);
        *(float4*)&Bs[brow][bc4] = bv;
        __syncthreads();
        #pragma unroll
        for (int kk = 0; kk < 16; ++kk) {
            float4 a4 = *(float4*)&As[kk][ty << 2];
            float4 b4 = *(float4*)&Bs[kk][tx << 2];
            float avr[4] = {a4.x, a4.y, a4.z, a4.w};
            float bvr[4] = {b4.x, b4.y, b4.z, b4.w};
            #pragma unroll
            for (int i = 0; i < 4; ++i)
                #pragma unroll
                for (int j = 0; j < 4; ++j)
                    acc[i][j] = fmaf(avr[i], bvr[j], acc[i][j]);
        }
        __syncthreads();
    }
    const int n = n0 + (tx << 2);
    float4 bv4 = make_float4(0.f, 0.f, 0.f, 0.f);
    if (bias) bv4 = *(const float4*)(bias + n);
    #pragma unroll
    for (int i = 0; i < 4; ++i) {
        int m = m0 + (ty << 2) + i;
        if (m >= M) continue;
        float v0 = acc[i][0] + bv4.x;
        float v1 = acc[i][1] + bv4.y;
        float v2 = acc[i][2] + bv4.z;
        float v3 = acc[i][3] + bv4.w;
        if (act == ACT_LRELU) {
            v0 = v0 > 0.f ? v0 : 0.01f * v0;
            v1 = v1 > 0.f ? v1 : 0.01f * v1;
            v2 = v2 > 0.f ? v2 : 0.01f * v2;
            v3 = v3 > 0.f ? v3 : 0.01f * v3;
        }
        *(float4*)(C + (size_t)m * N + n) = make_float4(v0, v1, v2, v3);
    }
}

// ---------------- weight prep ----------------
__global__ __launch_bounds__(256) void convert16_k(
    const float* __restrict__ in, ushort* __restrict__ out, int n)
{
    int i = blockIdx.x * 256 + threadIdx.x;
    if (i < n) out[i] = f2b(in[i]);
}
__global__ __launch_bounds__(256) void transpose16_k(
    const float* __restrict__ in, ushort* __restrict__ out, int k0, int KS, int N)
{
    int i = blockIdx.x * 256 + threadIdx.x;
    if (i >= KS * N) return;
    int k = i / N, n = i - k * N;
    out[(size_t)n * KS + k] = f2b(in[(size_t)(k0 + k) * N + n]);
}

// ---------------- pipelined bf16-A MFMA GEMM (steps 5/6/8) ----------------
__global__ __launch_bounds__(256) void gemm16p_k(
    const ushort* __restrict__ A16, const int* __restrict__ a_idx,
    const ushort* __restrict__ BT, const float* __restrict__ bias,
    float* __restrict__ C, ushort* __restrict__ C16,
    int M, int N, int K, int act)
{
    __shared__ ushort As[2][128 * 32];
    __shared__ ushort Bs[2][128 * 32];
    const int tid = threadIdx.x;
    const int l = tid & 63, w = tid >> 6;
    const int m0 = blockIdx.y * 128, n0 = blockIdx.x * 128;

    const ushort* agp[2];
    const ushort* bgp[2];
    #pragma unroll
    for (int j = 0; j < 2; ++j) {
        int row = j * 64 + w * 16 + (l >> 2);
        int seg = (l & 3) ^ (row & 3);
        int r = m0 + row; if (r >= M) r = M - 1;
        int rr = a_idx ? a_idx[r] : r;
        agp[j] = A16 + (size_t)rr * K + seg * 8;
        bgp[j] = BT + (size_t)(n0 + row) * K + seg * 8;
    }

    const int wm = (w & 1) * 64, wn = (w >> 1) * 64;
    const int cl = l & 15, q = l >> 4;
    const int sseg = (q ^ (cl & 3)) * 8;
    const int aoff = (wm + cl) * 32 + sseg;
    const int boff = (wn + cl) * 32 + sseg;

    floatx4 acc[4][4];
    #pragma unroll
    for (int mi = 0; mi < 4; ++mi)
        #pragma unroll
        for (int ni = 0; ni < 4; ++ni) acc[mi][ni] = 0.f;

    const int NT = K >> 5;
    #pragma unroll
    for (int j = 0; j < 2; ++j) {
        gload16(agp[j], &As[0][j * 2048 + w * 512]);
        gload16(bgp[j], &Bs[0][j * 2048 + w * 512]);
    }
    __syncthreads();

    int buf = 0;
    for (int t = 0; t < NT; ++t) {
        if (t + 1 < NT) {
            int k0 = (t + 1) * 32;
            #pragma unroll
            for (int j = 0; j < 2; ++j) {
                gload16(agp[j] + k0, &As[buf ^ 1][j * 2048 + w * 512]);
                gload16(bgp[j] + k0, &Bs[buf ^ 1][j * 2048 + w * 512]);
            }
        }
        short8 af[4], bf[4];
        #pragma unroll
        for (int mi = 0; mi < 4; ++mi) af[mi] = *(short8*)&As[buf][aoff + mi * 512];
        #pragma unroll
        for (int ni = 0; ni < 4; ++ni) bf[ni] = *(short8*)&Bs[buf][boff + ni * 512];
        #pragma unroll
        for (int mi = 0; mi < 4; ++mi)
            #pragma unroll
            for (int ni = 0; ni < 4; ++ni)
                acc[mi][ni] = __builtin_amdgcn_mfma_f32_16x16x32_bf16(
                    bf[ni], af[mi], acc[mi][ni], 0, 0, 0);
        __syncthreads();
        buf ^= 1;
    }

    #pragma unroll
    for (int mi = 0; mi < 4; ++mi) {
        int row = m0 + wm + mi * 16 + cl;
        if (row >= M) continue;
        #pragma unroll
        for (int ni = 0; ni < 4; ++ni) {
            int col = n0 + wn + ni * 16 + q * 4;
            float4 bv = bias ? *(const float4*)(bias + col)
                             : make_float4(0.f, 0.f, 0.f, 0.f);
            float v[4];
            #pragma unroll
            for (int r = 0; r < 4; ++r) {
                float x = acc[mi][ni][r] + ((const float*)&bv)[r];
                if (act == ACT_LRELU) x = x > 0.f ? x : 0.01f * x;
                v[r] = x;
            }
            if (C16) {
                ushort4 u;
                u.x = f2b(v[0]); u.y = f2b(v[1]); u.z = f2b(v[2]); u.w = f2b(v[3]);
                *(ushort4*)(C16 + (size_t)row * N + col) = u;
            }
            if (C) *(float4*)(C + (size_t)row * N + col) =
                       make_float4(v[0], v[1], v[2], v[3]);
        }
    }
}

// ---------------- wide fp32-A MFMA GEMM: 64x256 block, A read once (step 2) ----------------
__global__ __launch_bounds__(256) void gemm16pw_k(
    const float* __restrict__ A, const ushort* __restrict__ BT,
    const float* __restrict__ bias, ushort* __restrict__ C16,
    int M, int K, int act)      // N fixed = 256
{
    __shared__ ushort As[2][64 * 36];     // stride 36 -> 2-way banks
    __shared__ ushort Bs[2][256 * 32];    // gload_lds linear + XOR source
    const int tid = threadIdx.x;
    const int l = tid & 63, w = tid >> 6;
    const int m0 = blockIdx.x * 64;

    // A: thread covers row ar, K-slot af4 (8 floats = 2x float4 -> 16B bf16)
    const int ar = tid >> 2, af4 = tid & 3;
    int rr = m0 + ar; if (rr >= M) rr = M - 1;
    const float* agp = A + (size_t)rr * K + af4 * 8;
    const int awadr = ar * 36 + af4 * 8;

    const ushort* bgp[4];
    #pragma unroll
    for (int j = 0; j < 4; ++j) {
        int row = j * 64 + w * 16 + (l >> 2);
        int seg = (l & 3) ^ (row & 3);
        bgp[j] = BT + (size_t)row * K + seg * 8;
    }

    const int cl = l & 15, q = l >> 4;
    const int aoff = cl * 36 + q * 8;
    const int boff = (w * 64 + cl) * 32 + (q ^ (cl & 3)) * 8;

    floatx4 acc[4][4];
    #pragma unroll
    for (int mi = 0; mi < 4; ++mi)
        #pragma unroll
        for (int ni = 0; ni < 4; ++ni) acc[mi][ni] = 0.f;

    const int NT = K >> 5;
    #pragma unroll
    for (int j = 0; j < 4; ++j)
        gload16(bgp[j], &Bs[0][j * 2048 + w * 512]);
    {
        float4 v0 = *(const float4*)(agp);
        float4 v1 = *(const float4*)(agp + 4);
        ushort4 u0, u1;
        u0.x = f2b(v0.x); u0.y = f2b(v0.y); u0.z = f2b(v0.z); u0.w = f2b(v0.w);
        u1.x = f2b(v1.x); u1.y = f2b(v1.y); u1.z = f2b(v1.z); u1.w = f2b(v1.w);
        *(ushort4*)&As[0][awadr] = u0;
        *(ushort4*)&As[0][awadr + 4] = u1;
    }
    __syncthreads();

    int buf = 0;
    for (int t = 0; t < NT; ++t) {
        float4 v0, v1;
        if (t + 1 < NT) {
            int k0 = (t + 1) * 32;
            #pragma unroll
            for (int j = 0; j < 4; ++j)
                gload16(bgp[j] + k0, &Bs[buf ^ 1][j * 2048 + w * 512]);
            v0 = *(const float4*)(agp + k0);
            v1 = *(const float4*)(agp + k0 + 4);
        }
        short8 bf[4];
        #pragma unroll
        for (int ni = 0; ni < 4; ++ni) bf[ni] = *(short8*)&Bs[buf][boff + ni * 512];
        #pragma unroll
        for (int mi = 0; mi < 4; ++mi) {
            short8 af = *(short8*)&As[buf][aoff + mi * 576];
            #pragma unroll
            for (int ni = 0; ni < 4; ++ni)
                acc[mi][ni] = __builtin_amdgcn_mfma_f32_16x16x32_bf16(
                    bf[ni], af, acc[mi][ni], 0, 0, 0);
        }
        if (t + 1 < NT) {
            ushort4 u0, u1;
            u0.x = f2b(v0.x); u0.y = f2b(v0.y); u0.z = f2b(v0.z); u0.w = f2b(v0.w);
            u1.x = f2b(v1.x); u1.y = f2b(v1.y); u1.z = f2b(v1.z); u1.w = f2b(v1.w);
            *(ushort4*)&As[buf ^ 1][awadr] = u0;
            *(ushort4*)&As[buf ^ 1][awadr + 4] = u1;
        }
        __syncthreads();
        buf ^= 1;
    }

    #pragma unroll
    for (int mi = 0; mi < 4; ++mi) {
        int row = m0 + mi * 16 + cl;
        if (row >= M) continue;
        #pragma unroll
        for (int ni = 0; ni < 4; ++ni) {
            int col = w * 64 + ni * 16 + q * 4;
            float4 bv = bias ? *(const float4*)(bias + col)
                             : make_float4(0.f, 0.f, 0.f, 0.f);
            ushort4 u;
            float x0 = acc[mi][ni][0] + bv.x;
            float x1 = acc[mi][ni][1] + bv.y;
            float x2 = acc[mi][ni][2] + bv.z;
            float x3 = acc[mi][ni][3] + bv.w;
            if (act == ACT_LRELU) {
                x0 = x0 > 0.f ? x0 : 0.01f * x0;
                x1 = x1 > 0.f ? x1 : 0.01f * x1;
                x2 = x2 > 0.f ? x2 : 0.01f * x2;
                x3 = x3 > 0.f ? x3 : 0.01f * x3;
            }
            u.x = f2b(x0); u.y = f2b(x1); u.z = f2b(x2); u.w = f2b(x3);
            *(ushort4*)(C16 + (size_t)row * 256 + col) = u;
        }
    }
}

// ---------------- qdot[b] = query_repr[b] . rank_W[256:512] ----------------
__global__ __launch_bounds__(256) void qdot_k(
    const float* __restrict__ q, const float* __restrict__ rank_W,
    float* __restrict__ qdot)
{
    int b = blockIdx.x * 4 + (threadIdx.x >> 6);
    int l = threadIdx.x & 63;
    float s = 0.f;
    #pragma unroll
    for (int k = 0; k < 4; ++k) {
        int h = l + k * 64;
        s += q[(size_t)b * 256 + h] * rank_W[256 + h];
    }
    #pragma unroll
    for (int off = 32; off; off >>= 1) s += __shfl_xor(s, off, 64);
    if (l == 0) qdot[b] = s;
}

// ---------------- per-edge attention alpha, head-sorted order ----------------
__global__ __launch_bounds__(256) void alpha_k(
    const ushort* __restrict__ nodeWs16, const float* __restrict__ relWr,
    const float* __restrict__ relWqr, const float* __restrict__ bqr,
    const float* __restrict__ w_alpha, const float* __restrict__ b_alpha_p,
    const int* __restrict__ hcsr_hn, const int* __restrict__ hcsr_er,
    const int* __restrict__ hcsr_qr, const int* __restrict__ hcsr_e,
    float* __restrict__ alpha_out)
{
    const int tid = threadIdx.x;
    const int e0 = blockIdx.x * 32;
    __shared__ int hn[32], er[32], qr[32], se[32];
    if (tid < 32) {
        int i = e0 + tid;
        hn[tid] = hcsr_hn[i]; er[tid] = hcsr_er[i];
        qr[tid] = hcsr_qr[i]; se[tid] = hcsr_e[i];
    }
    __syncthreads();
    const int tx = tid & 63, ty = tid >> 6;
    const int c = tx * 4;
    const float4 bq = *(const float4*)(bqr + c);
    const float4 wa = *(const float4*)(w_alpha + c);
    float part[8];
    #pragma unroll
    for (int i2 = 0; i2 < 8; ++i2) {
        int i = ty * 8 + i2;
        ushort4 a16 = *(const ushort4*)(nodeWs16 + (size_t)hn[i] * 256 + c);
        float4 b = *(const float4*)(relWr + (size_t)er[i] * 256 + c);
        float4 d = *(const float4*)(relWqr + (size_t)qr[i] * 256 + c);
        float x0 = fmaxf(b2f(a16.x) + b.x + d.x + bq.x, 0.f);
        float x1 = fmaxf(b2f(a16.y) + b.y + d.y + bq.y, 0.f);
        float x2 = fmaxf(b2f(a16.z) + b.z + d.z + bq.z, 0.f);
        float x3 = fmaxf(b2f(a16.w) + b.w + d.w + bq.w, 0.f);
        part[i2] = x0 * wa.x + x1 * wa.y + x2 * wa.z + x3 * wa.w;
    }
    #pragma unroll
    for (int off = 32; off; off >>= 1)
        #pragma unroll
        for (int i2 = 0; i2 < 8; ++i2)
            part[i2] += __shfl_xor(part[i2], off, 64);
    if (tx == 0) {
        float ba = b_alpha_p[0];
        #pragma unroll
        for (int i2 = 0; i2 < 8; ++i2)
            alpha_out[se[ty * 8 + i2]] = 1.f / (1.f + __expf(-(part[i2] + ba)));
    }
}

// ---------------- CSR build ----------------
__global__ __launch_bounds__(256) void hist_k(
    const int* __restrict__ key, int* __restrict__ deg, int M)
{
    int e = blockIdx.x * 256 + threadIdx.x;
    if (e < M) atomicAdd(&deg[key[e]], 1);
}
__global__ __launch_bounds__(512) void scan1_k(
    const int* __restrict__ deg, int* __restrict__ partial, int N)
{
    __shared__ int sm[512];
    int i = blockIdx.x * 512 + threadIdx.x;
    sm[threadIdx.x] = (i < N) ? deg[i] : 0;
    __syncthreads();
    for (int off = 256; off; off >>= 1) {
        if (threadIdx.x < off) sm[threadIdx.x] += sm[threadIdx.x + off];
        __syncthreads();
    }
    if (threadIdx.x == 0) partial[blockIdx.x] = sm[0];
}
__global__ __launch_bounds__(256) void scan2_k(
    int* __restrict__ partial, int nPart, int* __restrict__ offsets, int N, int M)
{
    __shared__ int sm[256];
    int t = threadIdx.x;
    int v = (t < nPart) ? partial[t] : 0;
    sm[t] = v;
    __syncthreads();
    for (int off = 1; off < 256; off <<= 1) {
        int add = (t >= off) ? sm[t - off] : 0;
        __syncthreads();
        sm[t] += add;
        __syncthreads();
    }
    if (t < nPart) partial[t] = sm[t] - v;
    if (t == 0) offsets[N] = M;
}
__global__ __launch_bounds__(512) void scan3_k(
    const int* __restrict__ deg, const int* __restrict__ partial,
    int* __restrict__ offsets, int* __restrict__ cursor, int N)
{
    __shared__ int sm[512];
    int i = blockIdx.x * 512 + threadIdx.x;
    int t = threadIdx.x;
    int v = (i < N) ? deg[i] : 0;
    sm[t] = v;
    __syncthreads();
    for (int off = 1; off < 512; off <<= 1) {
        int add = (t >= off) ? sm[t - off] : 0;
        __syncthreads();
        sm[t] += add;
        __syncthreads();
    }
    if (i < N) {
        int excl = partial[blockIdx.x] + sm[t] - v;
        offsets[i] = excl;
        cursor[i] = excl;
    }
}
__global__ __launch_bounds__(256) void fill_k(
    const int* __restrict__ tail_node, const int* __restrict__ tail_ent,
    const int* __restrict__ edge_rel, const int* __restrict__ batch_idx,
    int* __restrict__ cursor, int* __restrict__ ce, int* __restrict__ cte,
    int* __restrict__ cer, int* __restrict__ ctn, int* __restrict__ cbi, int M)
{
    int e = blockIdx.x * 256 + threadIdx.x;
    if (e < M) {
        int tn = tail_node[e];
        int pos = atomicAdd(&cursor[tn], 1);
        ce[pos] = e; cte[pos] = tail_ent[e]; cer[pos] = edge_rel[e];
        ctn[pos] = tn; cbi[pos] = batch_idx[e];
    }
}
__global__ __launch_bounds__(256) void hfill_k(
    const int* __restrict__ head_node, const int* __restrict__ edge_rel,
    const int* __restrict__ query_rel, int* __restrict__ cursor,
    int* __restrict__ hhn, int* __restrict__ her, int* __restrict__ hqr,
    int* __restrict__ he, int M)
{
    int e = blockIdx.x * 256 + threadIdx.x;
    if (e < M) {
        int h = head_node[e];
        int pos = atomicAdd(&cursor[h], 1);
        hhn[pos] = h; her[pos] = edge_rel[e]; hqr[pos] = query_rel[e]; he[pos] = e;
    }
}

// ---------------- segment-sum via CSR gather-reduce ----------------
__global__ __launch_bounds__(256) void agg_csr_k(
    const float* __restrict__ relation_emb, const ushort* __restrict__ ent16,
    const float* __restrict__ alpha, const int* __restrict__ csr_e,
    const int* __restrict__ csr_er, const int* __restrict__ csr_te,
    const int* __restrict__ offsets, ushort* __restrict__ agg16)
{
    int node = blockIdx.x * 4 + (threadIdx.x >> 6);
    int lane = threadIdx.x & 63;
    int beg = offsets[node], end = offsets[node + 1];
    float4 acc = make_float4(0.f, 0.f, 0.f, 0.f);
    const int c = lane * 4;
    for (int j = beg; j < end; ++j) {
        float a = alpha[csr_e[j]];
        float4 v;
        if (lane < 32) {
            v = *(const float4*)(relation_emb + (size_t)csr_er[j] * 128 + c);
        } else {
            ushort4 u = *(const ushort4*)(ent16 + (size_t)csr_te[j] * 128 + (c - 128));
            v = make_float4(b2f(u.x), b2f(u.y), b2f(u.z), b2f(u.w));
        }
        acc.x += v.x * a; acc.y += v.y * a;
        acc.z += v.z * a; acc.w += v.w * a;
    }
    ushort4 o;
    o.x = f2b(acc.x); o.y = f2b(acc.y); o.z = f2b(acc.z); o.w = f2b(acc.w);
    *(ushort4*)(agg16 + (size_t)node * 256 + c) = o;
}

// ---------------- GRU elementwise + LayerNorm (all-bf16 I/O) ----------------
__global__ __launch_bounds__(256) void gru_ln_k(
    const ushort* __restrict__ gx, const ushort* __restrict__ gh,
    const ushort* __restrict__ h_prev, const float* __restrict__ ln_g,
    const float* __restrict__ ln_b, ushort* __restrict__ h_new16, int n0)
{
    int nl = blockIdx.x * 4 + (threadIdx.x >> 6);
    int lane = threadIdx.x & 63;
    int n = n0 + nl;
    const ushort* gxr = gx + (size_t)nl * 768;
    const ushort* ghr = gh + (size_t)nl * 768;
    const ushort* hpr = h_prev + (size_t)n * 256;
    float hv[4]; float s = 0.f, s2 = 0.f;
    #pragma unroll
    for (int q2 = 0; q2 < 4; ++q2) {
        int h = lane + q2 * 64;
        float xr = b2f(gxr[h]), xz = b2f(gxr[256 + h]), xn = b2f(gxr[512 + h]);
        float hr_ = b2f(ghr[h]), hn_ = b2f(ghr[512 + h]);
        float hz_ = b2f(ghr[256 + h]);
        float hp = b2f(hpr[h]);
        float r = 1.f / (1.f + __expf(-(xr + hr_)));
        float z = 1.f / (1.f + __expf(-(xz + hz_)));
        float nn = tanhf(xn + r * hn_);
        float v = (1.f - z) * nn + z * hp;
        hv[q2] = v; s += v; s2 += v * v;
    }
    #pragma unroll
    for (int off = 32; off; off >>= 1) {
        s  += __shfl_xor(s, off, 64);
        s2 += __shfl_xor(s2, off, 64);
    }
    float mean = s * (1.f / 256.f);
    float var  = s2 * (1.f / 256.f) - mean * mean;
    float rstd = rsqrtf(var + 1e-5f);
    ushort* outr = h_new16 + (size_t)n * 256;
    #pragma unroll
    for (int q2 = 0; q2 < 4; ++q2) {
        int h = lane + q2 * 64;
        outr[h] = f2b((hv[q2] - mean) * rstd * ln_g[h] + ln_b[h]);
    }
}

// ---------------- fused score v5: 128 edges/block, 4 col-passes, gload A ----------------
__global__ __launch_bounds__(256, 4) void score_mfma_k(
    const ushort* __restrict__ ent16, const ushort* __restrict__ candW1T,
    const ushort* __restrict__ relCand16, const ushort* __restrict__ hnewCand16,
    const float* __restrict__ rank_W, const float* __restrict__ rank_b_p,
    const float* __restrict__ qdot,
    const int* __restrict__ csr_e, const int* __restrict__ csr_te,
    const int* __restrict__ csr_er, const int* __restrict__ csr_tn,
    const int* __restrict__ csr_bi, float* __restrict__ scores, int M)
{
    // As layout: [kt][row][32] (kt = K/32 tile), slot XOR like gemm16p.
    __shared__ ushort As[128 * 128];          // 32 KB
    __shared__ int s_te[128], s_er[128], s_tn[128];
    __shared__ float s_part[4][128];
    const int tid = threadIdx.x;
    const int l = tid & 63, w = tid >> 6;
    const int e0 = blockIdx.x * 128;
    int cnt = M - e0; if (cnt > 128) cnt = 128;

    if (tid < 128) {
        int idx = e0 + (tid < cnt ? tid : 0);
        s_te[tid] = csr_te[idx];
        s_er[tid] = csr_er[idx];
        s_tn[tid] = csr_tn[idx];
    }
    __syncthreads();

    // stage A via gload_lds: chunk c = w*8+j covers ushorts [c*512, c*512+512)
    // = kt (c>>3), rows (c&7)*16 + (l>>2), slot l&3; source seg pre-swizzled.
    {
        const int lr = l >> 2, ls = l & 3;
        #pragma unroll
        for (int j = 0; j < 8; ++j) {
            int c = w * 8 + j;
            int kt = c >> 3;
            int row = (c & 7) * 16 + lr;
            int sg = kt * 4 + (ls ^ (row & 3));
            gload16(ent16 + (size_t)s_te[row] * 128 + sg * 8, &As[c * 512]);
        }
    }
    __syncthreads();

    const int cl = l & 15, q = l >> 4;
    const int sslot = (q ^ (cl & 3)) * 8;

    float rowsum[8];
    #pragma unroll
    for (int mi = 0; mi < 8; ++mi) rowsum[mi] = 0.f;

    #pragma unroll
    for (int ch = 0; ch < 4; ++ch) {
        floatx4 acc[8];
        #pragma unroll
        for (int mi = 0; mi < 8; ++mi) acc[mi] = 0.f;

        const ushort* bb = candW1T + (size_t)(w * 64 + ch * 16 + cl) * 128 + q * 8;
        #pragma unroll
        for (int kt = 0; kt < 4; ++kt) {
            short8 bf = *(const short8*)(bb + kt * 32);
            const int abase = kt * 4096 + cl * 32 + sslot;
            #pragma unroll
            for (int mi = 0; mi < 8; ++mi) {
                short8 af = *(short8*)&As[abase + mi * 512];
                acc[mi] = __builtin_amdgcn_mfma_f32_16x16x32_bf16(
                    bf, af, acc[mi], 0, 0, 0);
            }
        }
        // epilogue for this 16-col slice
        const int col = w * 64 + ch * 16 + q * 4;
        const float4 rw = *(const float4*)(rank_W + col);
        #pragma unroll
        for (int mi = 0; mi < 8; ++mi) {
            int row = mi * 16 + cl;
            int er = s_er[row], tn = s_tn[row];
            ushort4 rc = *(const ushort4*)(relCand16 + (size_t)er * 256 + col);
            ushort4 hc = *(const ushort4*)(hnewCand16 + (size_t)tn * 256 + col);
            float v0 = acc[mi][0] + b2f(rc.x) + b2f(hc.x);
            float v1 = acc[mi][1] + b2f(rc.y) + b2f(hc.y);
            float v2 = acc[mi][2] + b2f(rc.z) + b2f(hc.z);
            float v3 = acc[mi][3] + b2f(rc.w) + b2f(hc.w);
            v0 = v0 > 0.f ? v0 : 0.01f * v0;
            v1 = v1 > 0.f ? v1 : 0.01f * v1;
            v2 = v2 > 0.f ? v2 : 0.01f * v2;
            v3 = v3 > 0.f ? v3 : 0.01f * v3;
            rowsum[mi] += v0 * rw.x + v1 * rw.y + v2 * rw.z + v3 * rw.w;
        }
    }
    #pragma unroll
    for (int mi = 0; mi < 8; ++mi) {
        rowsum[mi] += __shfl_xor(rowsum[mi], 16, 64);
        rowsum[mi] += __shfl_xor(rowsum[mi], 32, 64);
    }
    if (q == 0) {
        #pragma unroll
        for (int mi = 0; mi < 8; ++mi)
            s_part[w][mi * 16 + cl] = rowsum[mi];
    }
    __syncthreads();
    if (tid < cnt) {
        int idx = e0 + tid;
        float s = s_part[0][tid] + s_part[1][tid] + s_part[2][tid] + s_part[3][tid]
                + qdot[csr_bi[idx]] + rank_b_p[0];
        scores[csr_e[idx]] = s;
    }
}

// ---------------------------------------------------------------------------
extern "C" void kernel_launch(void* const* d_in, const int* in_sizes, int n_in,
                              void* d_out, int out_size, void* d_ws, size_t ws_size,
                              hipStream_t stream)
{
    const float* entity_emb   = (const float*)d_in[0];
    const float* relation_emb = (const float*)d_in[1];
    const float* node_hidden  = (const float*)d_in[2];
    const float* query_repr   = (const float*)d_in[3];
    const float* Ws    = (const float*)d_in[4];
    const float* Wr    = (const float*)d_in[5];
    const float* Wqr   = (const float*)d_in[6];
    const float* bqr   = (const float*)d_in[7];
    const float* w_alpha = (const float*)d_in[8];
    const float* b_alpha = (const float*)d_in[9];
    const float* W_ih  = (const float*)d_in[10];
    const float* W_hh  = (const float*)d_in[11];
    const float* b_ih  = (const float*)d_in[12];
    const float* b_hh  = (const float*)d_in[13];
    const float* We2h_W = (const float*)d_in[14];
    const float* We2h_b = (const float*)d_in[15];
    const float* cand_W = (const float*)d_in[16];
    const float* cand_b = (const float*)d_in[17];
    const float* rank_W = (const float*)d_in[18];
    const float* rank_b = (const float*)d_in[19];
    const float* ln_g  = (const float*)d_in[20];
    const float* ln_b  = (const float*)d_in[21];
    const int* head_node = (const int*)d_in[22];
    const int* edge_rel  = (const int*)d_in[23];
    const int* tail_ent  = (const int*)d_in[24];
    const int* tail_node = (const int*)d_in[25];
    const int* query_rel = (const int*)d_in[26];
    const int* batch_idx = (const int*)d_in[27];
    const int* tail_node_ent = (const int*)d_in[28];
    float* out = (float*)d_out;
    (void)in_sizes; (void)n_in; (void)out_size; (void)ws_size;

    const int M = 200000, NNEW = 50000, NNODES = 100000, NREL = 500;
    const int NENT = 200000, E = 128;
    const int NCHUNK = 4, NC = NNEW / NCHUNK;   // 12500
    const int NP_T = (NNEW + 511) / 512;        // 98
    const int NP_H = (NNODES + 511) / 512;      // 196

    // ---- workspace layout (float units) ----
    float* w = (float*)d_ws;
    float* relWr    = w; w += NREL * 256;
    float* relWqr   = w; w += NREL * 256;
    float* relCand  = w; w += NREL * 256;
    float* qdot     = w; w += 256;
    float* alpha    = w; w += M;
    // bf16 tables (16B-aligned bases)
    ushort* h_prev16   = (ushort*)w; w += (size_t)NNEW * 256 / 2;
    ushort* agg16      = (ushort*)w; w += (size_t)NNEW * 256 / 2;
    ushort* hnewCand16 = (ushort*)w; w += (size_t)NNEW * 256 / 2;
    ushort* relCand16  = (ushort*)w; w += (NREL * 256) / 2;
    ushort* ent16      = (ushort*)w; w += (size_t)NENT * E / 2;
    ushort* h_new16    = (ushort*)w; w += (size_t)NNEW * 256 / 2;
    // bf16 weights
    ushort* W_ih16    = (ushort*)w; w += (768 * 256) / 2;
    ushort* W_hh16    = (ushort*)w; w += (768 * 256) / 2;
    ushort* WsT16     = (ushort*)w; w += (256 * 256) / 2;
    ushort* We2hT16   = (ushort*)w; w += (256 * 128) / 2;
    ushort* candW1T16 = (ushort*)w; w += (256 * 128) / 2;
    ushort* candW3T16 = (ushort*)w; w += (256 * 256) / 2;
    // ints
    int* deg      = (int*)w; w += NNEW;
    int* offsets  = (int*)w; w += NNEW + 1;
    int* cursor   = (int*)w; w += NNEW;
    int* deg2     = (int*)w; w += NNODES;
    int* offsets2 = (int*)w; w += NNODES + 1;
    int* cursor2  = (int*)w; w += NNODES;
    int* partial  = (int*)w; w += 512;
    int* csr_e  = (int*)w; w += M;
    int* csr_te = (int*)w; w += M;
    int* csr_er = (int*)w; w += M;
    int* csr_tn = (int*)w; w += M;
    int* csr_bi = (int*)w; w += M;
    int* hcsr_hn = (int*)w; w += M;
    int* hcsr_er = (int*)w; w += M;
    int* hcsr_qr = (int*)w; w += M;
    int* hcsr_e  = (int*)w; w += M;
    w = (float*)(((uintptr_t)w + 63) & ~(uintptr_t)63);
    // BIG region: phase 2-3: nodeWs16 (51.2 MB); phase 6-7: gx16|gh16 (38.4 MB)
    float* big = w;
    ushort* nodeWs16 = (ushort*)big;
    ushort* gx16 = (ushort*)big;
    ushort* gh16 = (ushort*)big + (size_t)NC * 768;

    // (0) tail CSR build (permuted attribute arrays)
    hipMemsetAsync(deg, 0, NNEW * sizeof(int), stream);
    hipMemsetAsync(deg2, 0, NNODES * sizeof(int), stream);
    hist_k<<<(M + 255) / 256, 256, 0, stream>>>(tail_node, deg, M);
    scan1_k<<<NP_T, 512, 0, stream>>>(deg, partial, NNEW);
    scan2_k<<<1, 256, 0, stream>>>(partial, NP_T, offsets, NNEW, M);
    scan3_k<<<NP_T, 512, 0, stream>>>(deg, partial, offsets, cursor, NNEW);
    fill_k<<<(M + 255) / 256, 256, 0, stream>>>(tail_node, tail_ent, edge_rel,
        batch_idx, cursor, csr_e, csr_te, csr_er, csr_tn, csr_bi, M);
    // head CSR build (for alpha locality)
    hist_k<<<(M + 255) / 256, 256, 0, stream>>>(head_node, deg2, M);
    scan1_k<<<NP_H, 512, 0, stream>>>(deg2, partial, NNODES);
    scan2_k<<<1, 256, 0, stream>>>(partial, NP_H, offsets2, NNODES, M);
    scan3_k<<<NP_H, 512, 0, stream>>>(deg2, partial, offsets2, cursor2, NNODES);
    hfill_k<<<(M + 255) / 256, 256, 0, stream>>>(head_node, edge_rel, query_rel,
        cursor2, hcsr_hn, hcsr_er, hcsr_qr, hcsr_e, M);

    // (1) weight prep + tables + qdot
    convert16_k<<<(NENT * E + 255) / 256, 256, 0, stream>>>(entity_emb, ent16, NENT * E);
    convert16_k<<<768, 256, 0, stream>>>(W_ih, W_ih16, 768 * 256);
    convert16_k<<<768, 256, 0, stream>>>(W_hh, W_hh16, 768 * 256);
    transpose16_k<<<256, 256, 0, stream>>>(Ws, WsT16, 0, 256, 256);
    transpose16_k<<<128, 256, 0, stream>>>(We2h_W, We2hT16, 0, 128, 256);
    transpose16_k<<<128, 256, 0, stream>>>(cand_W, candW1T16, 0, 128, 256);
    transpose16_k<<<256, 256, 0, stream>>>(cand_W, candW3T16, 256, 256, 256);
    gemm_k<<<dim3(8, 4), 256, 0, stream>>>(relation_emb, Wr,  nullptr, relWr,  NREL, 256, 128, nullptr, ACT_NONE);
    gemm_k<<<dim3(8, 4), 256, 0, stream>>>(relation_emb, Wqr, nullptr, relWqr, NREL, 256, 128, nullptr, ACT_NONE);
    gemm_k<<<dim3(8, 4), 256, 0, stream>>>(relation_emb, cand_W + 128 * 256, nullptr, relCand, NREL, 256, 128, nullptr, ACT_NONE);
    convert16_k<<<(NREL * 256 + 255) / 256, 256, 0, stream>>>(relCand, relCand16, NREL * 256);
    qdot_k<<<64, 256, 0, stream>>>(query_repr, rank_W, qdot);

    // (2) nodeWs16 = bf16(node_hidden @ Ws)   [64x256 block, A read once]
    gemm16pw_k<<<(NNODES + 63) / 64, 256, 0, stream>>>(
        node_hidden, WsT16, nullptr, nodeWs16, NNODES, 256, ACT_NONE);

    // (3) alpha (head-sorted)
    alpha_k<<<M / 32, 256, 0, stream>>>(nodeWs16, relWr, relWqr, bqr, w_alpha, b_alpha,
                                        hcsr_hn, hcsr_er, hcsr_qr, hcsr_e, alpha);

    // (4) segment sum via CSR
    agg_csr_k<<<NNEW / 4, 256, 0, stream>>>(relation_emb, ent16, alpha,
                                            csr_e, csr_er, csr_te, offsets, agg16);

    // (5) h_prev16 = bf16(lrelu(ent16[tail_node_ent] @ We2h_W + We2h_b))
    gemm16p_k<<<dim3(2, (NNEW + 127) / 128), 256, 0, stream>>>(
        ent16, tail_node_ent, We2hT16, We2h_b, nullptr, h_prev16, NNEW, 256, 128, ACT_LRELU);

    // (6,7) GRU chunks (gx16/gh16 alias big region — nodeWs16 dead after alpha)
    for (int ch = 0; ch < NCHUNK; ++ch) {
        int n0 = ch * NC;
        gemm16p_k<<<dim3(6, (NC + 127) / 128), 256, 0, stream>>>(
            agg16 + (size_t)n0 * 256, nullptr, W_ih16, b_ih, nullptr, gx16, NC, 768, 256, ACT_NONE);
        gemm16p_k<<<dim3(6, (NC + 127) / 128), 256, 0, stream>>>(
            h_prev16 + (size_t)n0 * 256, nullptr, W_hh16, b_hh, nullptr, gh16, NC, 768, 256, ACT_NONE);
        gru_ln_k<<<NC / 4, 256, 0, stream>>>(gx16, gh16, h_prev16, ln_g, ln_b, h_new16, n0);
    }

    // (8) hnewCand16 = bf16(h_new16 @ cand_W[256:512] + cand_b)
    gemm16p_k<<<dim3(2, (NNEW + 127) / 128), 256, 0, stream>>>(
        h_new16, nullptr, candW3T16, cand_b, nullptr, hnewCand16, NNEW, 256, 256, ACT_NONE);

    // (9) fused score (128 edges/block, CSR order)
    score_mfma_k<<<(M + 127) / 128, 256, 0, stream>>>(
        ent16, candW1T16, relCand16, hnewCand16, rank_W, rank_b, qdot,
        csr_e, csr_te, csr_er, csr_tn, csr_bi, out, M);
}

// Round 6
// 821.527 us; speedup vs baseline: 1.2224x; 1.2224x over previous
//
#include <hip/hip_runtime.h>
#include <math.h>

// ---------------------------------------------------------------------------
// CogKR pipeline, R9:
//  - score_mfma_k reverted to the measured-best v3 structure (64 edges/block,
//    VGPR ~80) with CSR-permuted attribute index loads. R8's launch_bounds(,4)
//    spill disaster removed.
//  - relprep_k: 3 relation GEMMs fused (blockIdx.z), relCand written bf16
//    directly (convert pass dropped).
//  - hist2_k: both CSR histograms in one pass.
//  - GRU chunks 4 -> 2 (big region 76.8 MB; ws ~245 MB).
//  - rest as R8: gemm16pw step2 (A once), all-bf16 GRU chain, head-sorted
//    alpha, permuted CSR attrs.
// ---------------------------------------------------------------------------

#define ACT_NONE 0
#define ACT_LRELU 1

typedef __attribute__((ext_vector_type(8))) short short8;
typedef __attribute__((ext_vector_type(4))) float floatx4;

__device__ __forceinline__ ushort f2b(float x) {
    union { float f; unsigned u; } v; v.f = x;
    return (ushort)((v.u + 0x7fffu + ((v.u >> 16) & 1u)) >> 16);
}
__device__ __forceinline__ float b2f(ushort b) {
    union { unsigned u; float f; } v; v.u = ((unsigned)b) << 16;
    return v.f;
}
__device__ __forceinline__ void gload16(const ushort* g, ushort* l) {
    __builtin_amdgcn_global_load_lds(
        (const __attribute__((address_space(1))) void*)g,
        (__attribute__((address_space(3))) void*)l, 16, 0, 0);
}

// ---------------- fused relation-table GEMM prep (z selects output) ----------------
// z=0: relWr = rel @ Wr (fp32);  z=1: relWqr = rel @ Wqr (fp32);
// z=2: relCand16 = bf16(rel @ cand_W[128:256]).
__global__ __launch_bounds__(256) void relprep_k(
    const float* __restrict__ A, const float* __restrict__ B0,
    const float* __restrict__ B1, const float* __restrict__ B2,
    float* __restrict__ C0, float* __restrict__ C1, ushort* __restrict__ C2,
    int M, int N, int K)
{
    __shared__ float As[16][68];
    __shared__ float Bs[16][68];
    const int z = blockIdx.z;
    const float* B = (z == 0) ? B0 : (z == 1) ? B1 : B2;
    const int tid = threadIdx.x;
    const int tx = tid & 15, ty = tid >> 4;
    const int m0 = blockIdx.x * 64, n0 = blockIdx.y * 64;
    float acc[4][4] = {};
    const int ar  = tid >> 2;
    const int ac4 = (tid & 3) * 4;
    const int brow = tid >> 4;
    const int bc4  = (tid & 15) * 4;
    const int gm = m0 + ar;
    const float* Arow = (gm < M) ? (A + (size_t)gm * K) : nullptr;
    for (int k0 = 0; k0 < K; k0 += 16) {
        float4 av = make_float4(0.f, 0.f, 0.f, 0.f);
        if (Arow) av = *(const float4*)(Arow + k0 + ac4);
        As[ac4 + 0][ar] = av.x;
        As[ac4 + 1][ar] = av.y;
        As[ac4 + 2][ar] = av.z;
        As[ac4 + 3][ar] = av.w;
        float4 bv = *(const float4*)(B + (size_t)(k0 + brow) * N + n0 + bc4);
        *(float4*)&Bs[brow][bc4] = bv;
        __syncthreads();
        #pragma unroll
        for (int kk = 0; kk < 16; ++kk) {
            float4 a4 = *(float4*)&As[kk][ty << 2];
            float4 b4 = *(float4*)&Bs[kk][tx << 2];
            float avr[4] = {a4.x, a4.y, a4.z, a4.w};
            float bvr[4] = {b4.x, b4.y, b4.z, b4.w};
            #pragma unroll
            for (int i = 0; i < 4; ++i)
                #pragma unroll
                for (int j = 0; j < 4; ++j)
                    acc[i][j] = fmaf(avr[i], bvr[j], acc[i][j]);
        }
        __syncthreads();
    }
    const int n = n0 + (tx << 2);
    #pragma unroll
    for (int i = 0; i < 4; ++i) {
        int m = m0 + (ty << 2) + i;
        if (m >= M) continue;
        if (z == 2) {
            ushort4 u;
            u.x = f2b(acc[i][0]); u.y = f2b(acc[i][1]);
            u.z = f2b(acc[i][2]); u.w = f2b(acc[i][3]);
            *(ushort4*)(C2 + (size_t)m * N + n) = u;
        } else {
            float* C = (z == 0) ? C0 : C1;
            *(float4*)(C + (size_t)m * N + n) =
                make_float4(acc[i][0], acc[i][1], acc[i][2], acc[i][3]);
        }
    }
}

// ---------------- weight prep ----------------
__global__ __launch_bounds__(256) void convert16_k(
    const float* __restrict__ in, ushort* __restrict__ out, int n)
{
    int i = blockIdx.x * 256 + threadIdx.x;
    if (i < n) out[i] = f2b(in[i]);
}
__global__ __launch_bounds__(256) void transpose16_k(
    const float* __restrict__ in, ushort* __restrict__ out, int k0, int KS, int N)
{
    int i = blockIdx.x * 256 + threadIdx.x;
    if (i >= KS * N) return;
    int k = i / N, n = i - k * N;
    out[(size_t)n * KS + k] = f2b(in[(size_t)(k0 + k) * N + n]);
}

// ---------------- pipelined bf16-A MFMA GEMM (steps 5/6/8) ----------------
__global__ __launch_bounds__(256) void gemm16p_k(
    const ushort* __restrict__ A16, const int* __restrict__ a_idx,
    const ushort* __restrict__ BT, const float* __restrict__ bias,
    float* __restrict__ C, ushort* __restrict__ C16,
    int M, int N, int K, int act)
{
    __shared__ ushort As[2][128 * 32];
    __shared__ ushort Bs[2][128 * 32];
    const int tid = threadIdx.x;
    const int l = tid & 63, w = tid >> 6;
    const int m0 = blockIdx.y * 128, n0 = blockIdx.x * 128;

    const ushort* agp[2];
    const ushort* bgp[2];
    #pragma unroll
    for (int j = 0; j < 2; ++j) {
        int row = j * 64 + w * 16 + (l >> 2);
        int seg = (l & 3) ^ (row & 3);
        int r = m0 + row; if (r >= M) r = M - 1;
        int rr = a_idx ? a_idx[r] : r;
        agp[j] = A16 + (size_t)rr * K + seg * 8;
        bgp[j] = BT + (size_t)(n0 + row) * K + seg * 8;
    }

    const int wm = (w & 1) * 64, wn = (w >> 1) * 64;
    const int cl = l & 15, q = l >> 4;
    const int sseg = (q ^ (cl & 3)) * 8;
    const int aoff = (wm + cl) * 32 + sseg;
    const int boff = (wn + cl) * 32 + sseg;

    floatx4 acc[4][4];
    #pragma unroll
    for (int mi = 0; mi < 4; ++mi)
        #pragma unroll
        for (int ni = 0; ni < 4; ++ni) acc[mi][ni] = 0.f;

    const int NT = K >> 5;
    #pragma unroll
    for (int j = 0; j < 2; ++j) {
        gload16(agp[j], &As[0][j * 2048 + w * 512]);
        gload16(bgp[j], &Bs[0][j * 2048 + w * 512]);
    }
    __syncthreads();

    int buf = 0;
    for (int t = 0; t < NT; ++t) {
        if (t + 1 < NT) {
            int k0 = (t + 1) * 32;
            #pragma unroll
            for (int j = 0; j < 2; ++j) {
                gload16(agp[j] + k0, &As[buf ^ 1][j * 2048 + w * 512]);
                gload16(bgp[j] + k0, &Bs[buf ^ 1][j * 2048 + w * 512]);
            }
        }
        short8 af[4], bf[4];
        #pragma unroll
        for (int mi = 0; mi < 4; ++mi) af[mi] = *(short8*)&As[buf][aoff + mi * 512];
        #pragma unroll
        for (int ni = 0; ni < 4; ++ni) bf[ni] = *(short8*)&Bs[buf][boff + ni * 512];
        #pragma unroll
        for (int mi = 0; mi < 4; ++mi)
            #pragma unroll
            for (int ni = 0; ni < 4; ++ni)
                acc[mi][ni] = __builtin_amdgcn_mfma_f32_16x16x32_bf16(
                    bf[ni], af[mi], acc[mi][ni], 0, 0, 0);
        __syncthreads();
        buf ^= 1;
    }

    #pragma unroll
    for (int mi = 0; mi < 4; ++mi) {
        int row = m0 + wm + mi * 16 + cl;
        if (row >= M) continue;
        #pragma unroll
        for (int ni = 0; ni < 4; ++ni) {
            int col = n0 + wn + ni * 16 + q * 4;
            float4 bv = bias ? *(const float4*)(bias + col)
                             : make_float4(0.f, 0.f, 0.f, 0.f);
            float v[4];
            #pragma unroll
            for (int r = 0; r < 4; ++r) {
                float x = acc[mi][ni][r] + ((const float*)&bv)[r];
                if (act == ACT_LRELU) x = x > 0.f ? x : 0.01f * x;
                v[r] = x;
            }
            if (C16) {
                ushort4 u;
                u.x = f2b(v[0]); u.y = f2b(v[1]); u.z = f2b(v[2]); u.w = f2b(v[3]);
                *(ushort4*)(C16 + (size_t)row * N + col) = u;
            }
            if (C) *(float4*)(C + (size_t)row * N + col) =
                       make_float4(v[0], v[1], v[2], v[3]);
        }
    }
}

// ---------------- wide fp32-A MFMA GEMM: 64x256 block, A read once (step 2) ----------------
__global__ __launch_bounds__(256) void gemm16pw_k(
    const float* __restrict__ A, const ushort* __restrict__ BT,
    const float* __restrict__ bias, ushort* __restrict__ C16,
    int M, int K, int act)      // N fixed = 256
{
    __shared__ ushort As[2][64 * 36];
    __shared__ ushort Bs[2][256 * 32];
    const int tid = threadIdx.x;
    const int l = tid & 63, w = tid >> 6;
    const int m0 = blockIdx.x * 64;

    const int ar = tid >> 2, af4 = tid & 3;
    int rr = m0 + ar; if (rr >= M) rr = M - 1;
    const float* agp = A + (size_t)rr * K + af4 * 8;
    const int awadr = ar * 36 + af4 * 8;

    const ushort* bgp[4];
    #pragma unroll
    for (int j = 0; j < 4; ++j) {
        int row = j * 64 + w * 16 + (l >> 2);
        int seg = (l & 3) ^ (row & 3);
        bgp[j] = BT + (size_t)row * K + seg * 8;
    }

    const int cl = l & 15, q = l >> 4;
    const int aoff = cl * 36 + q * 8;
    const int boff = (w * 64 + cl) * 32 + (q ^ (cl & 3)) * 8;

    floatx4 acc[4][4];
    #pragma unroll
    for (int mi = 0; mi < 4; ++mi)
        #pragma unroll
        for (int ni = 0; ni < 4; ++ni) acc[mi][ni] = 0.f;

    const int NT = K >> 5;
    #pragma unroll
    for (int j = 0; j < 4; ++j)
        gload16(bgp[j], &Bs[0][j * 2048 + w * 512]);
    {
        float4 v0 = *(const float4*)(agp);
        float4 v1 = *(const float4*)(agp + 4);
        ushort4 u0, u1;
        u0.x = f2b(v0.x); u0.y = f2b(v0.y); u0.z = f2b(v0.z); u0.w = f2b(v0.w);
        u1.x = f2b(v1.x); u1.y = f2b(v1.y); u1.z = f2b(v1.z); u1.w = f2b(v1.w);
        *(ushort4*)&As[0][awadr] = u0;
        *(ushort4*)&As[0][awadr + 4] = u1;
    }
    __syncthreads();

    int buf = 0;
    for (int t = 0; t < NT; ++t) {
        float4 v0, v1;
        if (t + 1 < NT) {
            int k0 = (t + 1) * 32;
            #pragma unroll
            for (int j = 0; j < 4; ++j)
                gload16(bgp[j] + k0, &Bs[buf ^ 1][j * 2048 + w * 512]);
            v0 = *(const float4*)(agp + k0);
            v1 = *(const float4*)(agp + k0 + 4);
        }
        short8 bf[4];
        #pragma unroll
        for (int ni = 0; ni < 4; ++ni) bf[ni] = *(short8*)&Bs[buf][boff + ni * 512];
        #pragma unroll
        for (int mi = 0; mi < 4; ++mi) {
            short8 af = *(short8*)&As[buf][aoff + mi * 576];
            #pragma unroll
            for (int ni = 0; ni < 4; ++ni)
                acc[mi][ni] = __builtin_amdgcn_mfma_f32_16x16x32_bf16(
                    bf[ni], af, acc[mi][ni], 0, 0, 0);
        }
        if (t + 1 < NT) {
            ushort4 u0, u1;
            u0.x = f2b(v0.x); u0.y = f2b(v0.y); u0.z = f2b(v0.z); u0.w = f2b(v0.w);
            u1.x = f2b(v1.x); u1.y = f2b(v1.y); u1.z = f2b(v1.z); u1.w = f2b(v1.w);
            *(ushort4*)&As[buf ^ 1][awadr] = u0;
            *(ushort4*)&As[buf ^ 1][awadr + 4] = u1;
        }
        __syncthreads();
        buf ^= 1;
    }

    #pragma unroll
    for (int mi = 0; mi < 4; ++mi) {
        int row = m0 + mi * 16 + cl;
        if (row >= M) continue;
        #pragma unroll
        for (int ni = 0; ni < 4; ++ni) {
            int col = w * 64 + ni * 16 + q * 4;
            float4 bv = bias ? *(const float4*)(bias + col)
                             : make_float4(0.f, 0.f, 0.f, 0.f);
            ushort4 u;
            float x0 = acc[mi][ni][0] + bv.x;
            float x1 = acc[mi][ni][1] + bv.y;
            float x2 = acc[mi][ni][2] + bv.z;
            float x3 = acc[mi][ni][3] + bv.w;
            if (act == ACT_LRELU) {
                x0 = x0 > 0.f ? x0 : 0.01f * x0;
                x1 = x1 > 0.f ? x1 : 0.01f * x1;
                x2 = x2 > 0.f ? x2 : 0.01f * x2;
                x3 = x3 > 0.f ? x3 : 0.01f * x3;
            }
            u.x = f2b(x0); u.y = f2b(x1); u.z = f2b(x2); u.w = f2b(x3);
            *(ushort4*)(C16 + (size_t)row * 256 + col) = u;
        }
    }
}

// ---------------- qdot[b] = query_repr[b] . rank_W[256:512] ----------------
__global__ __launch_bounds__(256) void qdot_k(
    const float* __restrict__ q, const float* __restrict__ rank_W,
    float* __restrict__ qdot)
{
    int b = blockIdx.x * 4 + (threadIdx.x >> 6);
    int l = threadIdx.x & 63;
    float s = 0.f;
    #pragma unroll
    for (int k = 0; k < 4; ++k) {
        int h = l + k * 64;
        s += q[(size_t)b * 256 + h] * rank_W[256 + h];
    }
    #pragma unroll
    for (int off = 32; off; off >>= 1) s += __shfl_xor(s, off, 64);
    if (l == 0) qdot[b] = s;
}

// ---------------- per-edge attention alpha, head-sorted order ----------------
__global__ __launch_bounds__(256) void alpha_k(
    const ushort* __restrict__ nodeWs16, const float* __restrict__ relWr,
    const float* __restrict__ relWqr, const float* __restrict__ bqr,
    const float* __restrict__ w_alpha, const float* __restrict__ b_alpha_p,
    const int* __restrict__ hcsr_hn, const int* __restrict__ hcsr_er,
    const int* __restrict__ hcsr_qr, const int* __restrict__ hcsr_e,
    float* __restrict__ alpha_out)
{
    const int tid = threadIdx.x;
    const int e0 = blockIdx.x * 32;
    __shared__ int hn[32], er[32], qr[32], se[32];
    if (tid < 32) {
        int i = e0 + tid;
        hn[tid] = hcsr_hn[i]; er[tid] = hcsr_er[i];
        qr[tid] = hcsr_qr[i]; se[tid] = hcsr_e[i];
    }
    __syncthreads();
    const int tx = tid & 63, ty = tid >> 6;
    const int c = tx * 4;
    const float4 bq = *(const float4*)(bqr + c);
    const float4 wa = *(const float4*)(w_alpha + c);
    float part[8];
    #pragma unroll
    for (int i2 = 0; i2 < 8; ++i2) {
        int i = ty * 8 + i2;
        ushort4 a16 = *(const ushort4*)(nodeWs16 + (size_t)hn[i] * 256 + c);
        float4 b = *(const float4*)(relWr + (size_t)er[i] * 256 + c);
        float4 d = *(const float4*)(relWqr + (size_t)qr[i] * 256 + c);
        float x0 = fmaxf(b2f(a16.x) + b.x + d.x + bq.x, 0.f);
        float x1 = fmaxf(b2f(a16.y) + b.y + d.y + bq.y, 0.f);
        float x2 = fmaxf(b2f(a16.z) + b.z + d.z + bq.z, 0.f);
        float x3 = fmaxf(b2f(a16.w) + b.w + d.w + bq.w, 0.f);
        part[i2] = x0 * wa.x + x1 * wa.y + x2 * wa.z + x3 * wa.w;
    }
    #pragma unroll
    for (int off = 32; off; off >>= 1)
        #pragma unroll
        for (int i2 = 0; i2 < 8; ++i2)
            part[i2] += __shfl_xor(part[i2], off, 64);
    if (tx == 0) {
        float ba = b_alpha_p[0];
        #pragma unroll
        for (int i2 = 0; i2 < 8; ++i2)
            alpha_out[se[ty * 8 + i2]] = 1.f / (1.f + __expf(-(part[i2] + ba)));
    }
}

// ---------------- CSR build ----------------
__global__ __launch_bounds__(256) void hist2_k(
    const int* __restrict__ tail_node, const int* __restrict__ head_node,
    int* __restrict__ deg_t, int* __restrict__ deg_h, int M)
{
    int e = blockIdx.x * 256 + threadIdx.x;
    if (e < M) {
        atomicAdd(&deg_t[tail_node[e]], 1);
        atomicAdd(&deg_h[head_node[e]], 1);
    }
}
__global__ __launch_bounds__(512) void scan1_k(
    const int* __restrict__ deg, int* __restrict__ partial, int N)
{
    __shared__ int sm[512];
    int i = blockIdx.x * 512 + threadIdx.x;
    sm[threadIdx.x] = (i < N) ? deg[i] : 0;
    __syncthreads();
    for (int off = 256; off; off >>= 1) {
        if (threadIdx.x < off) sm[threadIdx.x] += sm[threadIdx.x + off];
        __syncthreads();
    }
    if (threadIdx.x == 0) partial[blockIdx.x] = sm[0];
}
__global__ __launch_bounds__(256) void scan2_k(
    int* __restrict__ partial, int nPart, int* __restrict__ offsets, int N, int M)
{
    __shared__ int sm[256];
    int t = threadIdx.x;
    int v = (t < nPart) ? partial[t] : 0;
    sm[t] = v;
    __syncthreads();
    for (int off = 1; off < 256; off <<= 1) {
        int add = (t >= off) ? sm[t - off] : 0;
        __syncthreads();
        sm[t] += add;
        __syncthreads();
    }
    if (t < nPart) partial[t] = sm[t] - v;
    if (t == 0) offsets[N] = M;
}
__global__ __launch_bounds__(512) void scan3_k(
    const int* __restrict__ deg, const int* __restrict__ partial,
    int* __restrict__ offsets, int* __restrict__ cursor, int N)
{
    __shared__ int sm[512];
    int i = blockIdx.x * 512 + threadIdx.x;
    int t = threadIdx.x;
    int v = (i < N) ? deg[i] : 0;
    sm[t] = v;
    __syncthreads();
    for (int off = 1; off < 512; off <<= 1) {
        int add = (t >= off) ? sm[t - off] : 0;
        __syncthreads();
        sm[t] += add;
        __syncthreads();
    }
    if (i < N) {
        int excl = partial[blockIdx.x] + sm[t] - v;
        offsets[i] = excl;
        cursor[i] = excl;
    }
}
__global__ __launch_bounds__(256) void fill_k(
    const int* __restrict__ tail_node, const int* __restrict__ tail_ent,
    const int* __restrict__ edge_rel, const int* __restrict__ batch_idx,
    int* __restrict__ cursor, int* __restrict__ ce, int* __restrict__ cte,
    int* __restrict__ cer, int* __restrict__ ctn, int* __restrict__ cbi, int M)
{
    int e = blockIdx.x * 256 + threadIdx.x;
    if (e < M) {
        int tn = tail_node[e];
        int pos = atomicAdd(&cursor[tn], 1);
        ce[pos] = e; cte[pos] = tail_ent[e]; cer[pos] = edge_rel[e];
        ctn[pos] = tn; cbi[pos] = batch_idx[e];
    }
}
__global__ __launch_bounds__(256) void hfill_k(
    const int* __restrict__ head_node, const int* __restrict__ edge_rel,
    const int* __restrict__ query_rel, int* __restrict__ cursor,
    int* __restrict__ hhn, int* __restrict__ her, int* __restrict__ hqr,
    int* __restrict__ he, int M)
{
    int e = blockIdx.x * 256 + threadIdx.x;
    if (e < M) {
        int h = head_node[e];
        int pos = atomicAdd(&cursor[h], 1);
        hhn[pos] = h; her[pos] = edge_rel[e]; hqr[pos] = query_rel[e]; he[pos] = e;
    }
}

// ---------------- segment-sum via CSR gather-reduce ----------------
__global__ __launch_bounds__(256) void agg_csr_k(
    const float* __restrict__ relation_emb, const ushort* __restrict__ ent16,
    const float* __restrict__ alpha, const int* __restrict__ csr_e,
    const int* __restrict__ csr_er, const int* __restrict__ csr_te,
    const int* __restrict__ offsets, ushort* __restrict__ agg16)
{
    int node = blockIdx.x * 4 + (threadIdx.x >> 6);
    int lane = threadIdx.x & 63;
    int beg = offsets[node], end = offsets[node + 1];
    float4 acc = make_float4(0.f, 0.f, 0.f, 0.f);
    const int c = lane * 4;
    for (int j = beg; j < end; ++j) {
        float a = alpha[csr_e[j]];
        float4 v;
        if (lane < 32) {
            v = *(const float4*)(relation_emb + (size_t)csr_er[j] * 128 + c);
        } else {
            ushort4 u = *(const ushort4*)(ent16 + (size_t)csr_te[j] * 128 + (c - 128));
            v = make_float4(b2f(u.x), b2f(u.y), b2f(u.z), b2f(u.w));
        }
        acc.x += v.x * a; acc.y += v.y * a;
        acc.z += v.z * a; acc.w += v.w * a;
    }
    ushort4 o;
    o.x = f2b(acc.x); o.y = f2b(acc.y); o.z = f2b(acc.z); o.w = f2b(acc.w);
    *(ushort4*)(agg16 + (size_t)node * 256 + c) = o;
}

// ---------------- GRU elementwise + LayerNorm (all-bf16 I/O) ----------------
__global__ __launch_bounds__(256) void gru_ln_k(
    const ushort* __restrict__ gx, const ushort* __restrict__ gh,
    const ushort* __restrict__ h_prev, const float* __restrict__ ln_g,
    const float* __restrict__ ln_b, ushort* __restrict__ h_new16, int n0)
{
    int nl = blockIdx.x * 4 + (threadIdx.x >> 6);
    int lane = threadIdx.x & 63;
    int n = n0 + nl;
    const ushort* gxr = gx + (size_t)nl * 768;
    const ushort* ghr = gh + (size_t)nl * 768;
    const ushort* hpr = h_prev + (size_t)n * 256;
    float hv[4]; float s = 0.f, s2 = 0.f;
    #pragma unroll
    for (int q2 = 0; q2 < 4; ++q2) {
        int h = lane + q2 * 64;
        float xr = b2f(gxr[h]), xz = b2f(gxr[256 + h]), xn = b2f(gxr[512 + h]);
        float hr_ = b2f(ghr[h]), hn_ = b2f(ghr[512 + h]);
        float hz_ = b2f(ghr[256 + h]);
        float hp = b2f(hpr[h]);
        float r = 1.f / (1.f + __expf(-(xr + hr_)));
        float z = 1.f / (1.f + __expf(-(xz + hz_)));
        float nn = tanhf(xn + r * hn_);
        float v = (1.f - z) * nn + z * hp;
        hv[q2] = v; s += v; s2 += v * v;
    }
    #pragma unroll
    for (int off = 32; off; off >>= 1) {
        s  += __shfl_xor(s, off, 64);
        s2 += __shfl_xor(s2, off, 64);
    }
    float mean = s * (1.f / 256.f);
    float var  = s2 * (1.f / 256.f) - mean * mean;
    float rstd = rsqrtf(var + 1e-5f);
    ushort* outr = h_new16 + (size_t)n * 256;
    #pragma unroll
    for (int q2 = 0; q2 < 4; ++q2) {
        int h = lane + q2 * 64;
        outr[h] = f2b((hv[q2] - mean) * rstd * ln_g[h] + ln_b[h]);
    }
}

// ---------------- fused score (v3 structure, 64 edges/block, perm attrs) ----------------
__global__ __launch_bounds__(256) void score_mfma_k(
    const ushort* __restrict__ ent16, const ushort* __restrict__ candW1T,
    const ushort* __restrict__ relCand16, const ushort* __restrict__ hnewCand16,
    const float* __restrict__ rank_W, const float* __restrict__ rank_b_p,
    const float* __restrict__ qdot,
    const int* __restrict__ csr_e, const int* __restrict__ csr_te,
    const int* __restrict__ csr_er, const int* __restrict__ csr_tn,
    const int* __restrict__ csr_bi, float* __restrict__ scores)
{
    __shared__ ushort As[64 * 136];
    __shared__ int s_er[64], s_tn[64];
    __shared__ float s_part[4][64];
    const int tid = threadIdx.x;
    const int e0 = blockIdx.x * 64;
    __shared__ int s_te[64];
    if (tid < 64) {
        int idx = e0 + tid;
        s_te[tid] = csr_te[idx];
        s_er[tid] = csr_er[idx];
        s_tn[tid] = csr_tn[idx];
    }
    __syncthreads();

    // stage A: 4 threads/row x 4 segs (16 segs/row, K=128 full coverage)
    {
        const int row = tid >> 2, s0 = tid & 3;
        const ushort* ar = ent16 + (size_t)s_te[row] * 128;
        #pragma unroll
        for (int j = 0; j < 4; ++j) {
            int seg = s0 + j * 4;
            *(uint4*)&As[row * 136 + seg * 8] = *(const uint4*)(ar + seg * 8);
        }
    }
    __syncthreads();

    const int l = tid & 63, w = tid >> 6;
    const int cl = l & 15, q = l >> 4;

    floatx4 acc[4][4];
    #pragma unroll
    for (int mi = 0; mi < 4; ++mi)
        #pragma unroll
        for (int ni = 0; ni < 4; ++ni) acc[mi][ni] = 0.f;

    const ushort* bbase = candW1T + (size_t)(w * 64 + cl) * 128 + q * 8;

    for (int k0 = 0; k0 < 128; k0 += 32) {
        short8 af[4], bf[4];
        #pragma unroll
        for (int ni = 0; ni < 4; ++ni)
            bf[ni] = *(const short8*)(bbase + ni * 2048 + k0);
        #pragma unroll
        for (int mi = 0; mi < 4; ++mi)
            af[mi] = *(short8*)&As[(mi * 16 + cl) * 136 + k0 + q * 8];
        // swapped operands: acc[mi][ni] = C^T tile
        #pragma unroll
        for (int mi = 0; mi < 4; ++mi)
            #pragma unroll
            for (int ni = 0; ni < 4; ++ni)
                acc[mi][ni] = __builtin_amdgcn_mfma_f32_16x16x32_bf16(
                    bf[ni], af[mi], acc[mi][ni], 0, 0, 0);
    }

    // epilogue: lane(cl,q) owns row mi*16+cl, cols w*64+ni*16+q*4+{0..3}
    float rowsum[4];
    #pragma unroll
    for (int mi = 0; mi < 4; ++mi) {
        int row = mi * 16 + cl;
        int er = s_er[row], tn = s_tn[row];
        float rs = 0.f;
        #pragma unroll
        for (int ni = 0; ni < 4; ++ni) {
            int col = w * 64 + ni * 16 + q * 4;
            ushort4 rc = *(const ushort4*)(relCand16 + (size_t)er * 256 + col);
            ushort4 hc = *(const ushort4*)(hnewCand16 + (size_t)tn * 256 + col);
            float4 rw = *(const float4*)(rank_W + col);
            float v0 = acc[mi][ni][0] + b2f(rc.x) + b2f(hc.x);
            float v1 = acc[mi][ni][1] + b2f(rc.y) + b2f(hc.y);
            float v2 = acc[mi][ni][2] + b2f(rc.z) + b2f(hc.z);
            float v3 = acc[mi][ni][3] + b2f(rc.w) + b2f(hc.w);
            v0 = v0 > 0.f ? v0 : 0.01f * v0;
            v1 = v1 > 0.f ? v1 : 0.01f * v1;
            v2 = v2 > 0.f ? v2 : 0.01f * v2;
            v3 = v3 > 0.f ? v3 : 0.01f * v3;
            rs += v0 * rw.x + v1 * rw.y + v2 * rw.z + v3 * rw.w;
        }
        rowsum[mi] = rs;
    }
    #pragma unroll
    for (int mi = 0; mi < 4; ++mi) {
        rowsum[mi] += __shfl_xor(rowsum[mi], 16, 64);
        rowsum[mi] += __shfl_xor(rowsum[mi], 32, 64);
    }
    if (q == 0) {
        #pragma unroll
        for (int mi = 0; mi < 4; ++mi)
            s_part[w][mi * 16 + cl] = rowsum[mi];
    }
    __syncthreads();
    if (tid < 64) {
        int idx = e0 + tid;
        float s = s_part[0][tid] + s_part[1][tid] + s_part[2][tid] + s_part[3][tid]
                + qdot[csr_bi[idx]] + rank_b_p[0];
        scores[csr_e[idx]] = s;
    }
}

// ---------------------------------------------------------------------------
extern "C" void kernel_launch(void* const* d_in, const int* in_sizes, int n_in,
                              void* d_out, int out_size, void* d_ws, size_t ws_size,
                              hipStream_t stream)
{
    const float* entity_emb   = (const float*)d_in[0];
    const float* relation_emb = (const float*)d_in[1];
    const float* node_hidden  = (const float*)d_in[2];
    const float* query_repr   = (const float*)d_in[3];
    const float* Ws    = (const float*)d_in[4];
    const float* Wr    = (const float*)d_in[5];
    const float* Wqr   = (const float*)d_in[6];
    const float* bqr   = (const float*)d_in[7];
    const float* w_alpha = (const float*)d_in[8];
    const float* b_alpha = (const float*)d_in[9];
    const float* W_ih  = (const float*)d_in[10];
    const float* W_hh  = (const float*)d_in[11];
    const float* b_ih  = (const float*)d_in[12];
    const float* b_hh  = (const float*)d_in[13];
    const float* We2h_W = (const float*)d_in[14];
    const float* We2h_b = (const float*)d_in[15];
    const float* cand_W = (const float*)d_in[16];
    const float* cand_b = (const float*)d_in[17];
    const float* rank_W = (const float*)d_in[18];
    const float* rank_b = (const float*)d_in[19];
    const float* ln_g  = (const float*)d_in[20];
    const float* ln_b  = (const float*)d_in[21];
    const int* head_node = (const int*)d_in[22];
    const int* edge_rel  = (const int*)d_in[23];
    const int* tail_ent  = (const int*)d_in[24];
    const int* tail_node = (const int*)d_in[25];
    const int* query_rel = (const int*)d_in[26];
    const int* batch_idx = (const int*)d_in[27];
    const int* tail_node_ent = (const int*)d_in[28];
    float* out = (float*)d_out;
    (void)in_sizes; (void)n_in; (void)out_size; (void)ws_size;

    const int M = 200000, NNEW = 50000, NNODES = 100000, NREL = 500;
    const int NENT = 200000, E = 128;
    const int NCHUNK = 2, NC = NNEW / NCHUNK;   // 25000
    const int NP_T = (NNEW + 511) / 512;        // 98
    const int NP_H = (NNODES + 511) / 512;      // 196

    // ---- workspace layout (float units) ----
    float* w = (float*)d_ws;
    float* relWr    = w; w += NREL * 256;
    float* relWqr   = w; w += NREL * 256;
    float* qdot     = w; w += 256;
    float* alpha    = w; w += M;
    // bf16 tables (16B-aligned bases)
    ushort* h_prev16   = (ushort*)w; w += (size_t)NNEW * 256 / 2;
    ushort* agg16      = (ushort*)w; w += (size_t)NNEW * 256 / 2;
    ushort* hnewCand16 = (ushort*)w; w += (size_t)NNEW * 256 / 2;
    ushort* relCand16  = (ushort*)w; w += (NREL * 256) / 2;
    ushort* ent16      = (ushort*)w; w += (size_t)NENT * E / 2;
    ushort* h_new16    = (ushort*)w; w += (size_t)NNEW * 256 / 2;
    // bf16 weights
    ushort* W_ih16    = (ushort*)w; w += (768 * 256) / 2;
    ushort* W_hh16    = (ushort*)w; w += (768 * 256) / 2;
    ushort* WsT16     = (ushort*)w; w += (256 * 256) / 2;
    ushort* We2hT16   = (ushort*)w; w += (256 * 128) / 2;
    ushort* candW1T16 = (ushort*)w; w += (256 * 128) / 2;
    ushort* candW3T16 = (ushort*)w; w += (256 * 256) / 2;
    // ints
    int* deg      = (int*)w; w += NNEW;
    int* offsets  = (int*)w; w += NNEW + 1;
    int* cursor   = (int*)w; w += NNEW;
    int* deg2     = (int*)w; w += NNODES;
    int* offsets2 = (int*)w; w += NNODES + 1;
    int* cursor2  = (int*)w; w += NNODES;
    int* partial  = (int*)w; w += 512;
    int* csr_e  = (int*)w; w += M;
    int* csr_te = (int*)w; w += M;
    int* csr_er = (int*)w; w += M;
    int* csr_tn = (int*)w; w += M;
    int* csr_bi = (int*)w; w += M;
    int* hcsr_hn = (int*)w; w += M;
    int* hcsr_er = (int*)w; w += M;
    int* hcsr_qr = (int*)w; w += M;
    int* hcsr_e  = (int*)w; w += M;
    w = (float*)(((uintptr_t)w + 63) & ~(uintptr_t)63);
    // BIG region: phase 2-3: nodeWs16 (51.2 MB); phase 6-7: gx16|gh16 (76.8 MB)
    float* big = w;
    ushort* nodeWs16 = (ushort*)big;
    ushort* gx16 = (ushort*)big;
    ushort* gh16 = (ushort*)big + (size_t)NC * 768;

    // (0) CSR builds (fused histogram; permuted attribute arrays)
    hipMemsetAsync(deg, 0, NNEW * sizeof(int), stream);
    hipMemsetAsync(deg2, 0, NNODES * sizeof(int), stream);
    hist2_k<<<(M + 255) / 256, 256, 0, stream>>>(tail_node, head_node, deg, deg2, M);
    scan1_k<<<NP_T, 512, 0, stream>>>(deg, partial, NNEW);
    scan2_k<<<1, 256, 0, stream>>>(partial, NP_T, offsets, NNEW, M);
    scan3_k<<<NP_T, 512, 0, stream>>>(deg, partial, offsets, cursor, NNEW);
    fill_k<<<(M + 255) / 256, 256, 0, stream>>>(tail_node, tail_ent, edge_rel,
        batch_idx, cursor, csr_e, csr_te, csr_er, csr_tn, csr_bi, M);
    scan1_k<<<NP_H, 512, 0, stream>>>(deg2, partial, NNODES);
    scan2_k<<<1, 256, 0, stream>>>(partial, NP_H, offsets2, NNODES, M);
    scan3_k<<<NP_H, 512, 0, stream>>>(deg2, partial, offsets2, cursor2, NNODES);
    hfill_k<<<(M + 255) / 256, 256, 0, stream>>>(head_node, edge_rel, query_rel,
        cursor2, hcsr_hn, hcsr_er, hcsr_qr, hcsr_e, M);

    // (1) weight prep + tables + qdot
    convert16_k<<<(NENT * E + 255) / 256, 256, 0, stream>>>(entity_emb, ent16, NENT * E);
    convert16_k<<<768, 256, 0, stream>>>(W_ih, W_ih16, 768 * 256);
    convert16_k<<<768, 256, 0, stream>>>(W_hh, W_hh16, 768 * 256);
    transpose16_k<<<256, 256, 0, stream>>>(Ws, WsT16, 0, 256, 256);
    transpose16_k<<<128, 256, 0, stream>>>(We2h_W, We2hT16, 0, 128, 256);
    transpose16_k<<<128, 256, 0, stream>>>(cand_W, candW1T16, 0, 128, 256);
    transpose16_k<<<256, 256, 0, stream>>>(cand_W, candW3T16, 256, 256, 256);
    relprep_k<<<dim3(8, 4, 3), 256, 0, stream>>>(
        relation_emb, Wr, Wqr, cand_W + 128 * 256,
        relWr, relWqr, relCand16, NREL, 256, 128);
    qdot_k<<<64, 256, 0, stream>>>(query_repr, rank_W, qdot);

    // (2) nodeWs16 = bf16(node_hidden @ Ws)   [64x256 block, A read once]
    gemm16pw_k<<<(NNODES + 63) / 64, 256, 0, stream>>>(
        node_hidden, WsT16, nullptr, nodeWs16, NNODES, 256, ACT_NONE);

    // (3) alpha (head-sorted)
    alpha_k<<<M / 32, 256, 0, stream>>>(nodeWs16, relWr, relWqr, bqr, w_alpha, b_alpha,
                                        hcsr_hn, hcsr_er, hcsr_qr, hcsr_e, alpha);

    // (4) segment sum via CSR
    agg_csr_k<<<NNEW / 4, 256, 0, stream>>>(relation_emb, ent16, alpha,
                                            csr_e, csr_er, csr_te, offsets, agg16);

    // (5) h_prev16 = bf16(lrelu(ent16[tail_node_ent] @ We2h_W + We2h_b))
    gemm16p_k<<<dim3(2, (NNEW + 127) / 128), 256, 0, stream>>>(
        ent16, tail_node_ent, We2hT16, We2h_b, nullptr, h_prev16, NNEW, 256, 128, ACT_LRELU);

    // (6,7) GRU chunks (gx16/gh16 alias big region — nodeWs16 dead after alpha)
    for (int ch = 0; ch < NCHUNK; ++ch) {
        int n0 = ch * NC;
        gemm16p_k<<<dim3(6, (NC + 127) / 128), 256, 0, stream>>>(
            agg16 + (size_t)n0 * 256, nullptr, W_ih16, b_ih, nullptr, gx16, NC, 768, 256, ACT_NONE);
        gemm16p_k<<<dim3(6, (NC + 127) / 128), 256, 0, stream>>>(
            h_prev16 + (size_t)n0 * 256, nullptr, W_hh16, b_hh, nullptr, gh16, NC, 768, 256, ACT_NONE);
        gru_ln_k<<<NC / 4, 256, 0, stream>>>(gx16, gh16, h_prev16, ln_g, ln_b, h_new16, n0);
    }

    // (8) hnewCand16 = bf16(h_new16 @ cand_W[256:512] + cand_b)
    gemm16p_k<<<dim3(2, (NNEW + 127) / 128), 256, 0, stream>>>(
        h_new16, nullptr, candW3T16, cand_b, nullptr, hnewCand16, NNEW, 256, 256, ACT_NONE);

    // (9) fused score (64 edges/block, v3 structure, CSR order)
    score_mfma_k<<<M / 64, 256, 0, stream>>>(
        ent16, candW1T16, relCand16, hnewCand16, rank_W, rank_b, qdot,
        csr_e, csr_te, csr_er, csr_tn, csr_bi, out);
}

// Round 7
// 803.315 us; speedup vs baseline: 1.2501x; 1.0227x over previous
//
#include <hip/hip_runtime.h>
#include <math.h>

// ---------------------------------------------------------------------------
// CogKR pipeline, R10:
//  - score_mfma_k v3.1: no index-LDS/barrier-1, per-lane coalesced index
//    loads, depth-2 ring prefetch of relCand/hnewCand epilogue gathers
//    (batch0 hidden under the MFMA K-loop).
//  - gruln_cand_k: GRU + LayerNorm + (h_new @ candW3 + cand_b) fused;
//    h_new16 buffer and step-8 GEMM removed.
//  - agg_csr_k: 2-edge unrolled reduce loop (latency ILP).
//  - convertW_k / transpose4_k: prep launches fused.
//  - rest as R9 (permuted CSR attrs, all-bf16 GRU inputs, head-sorted alpha,
//    relprep fused GEMM, gemm16pw step2).
// ---------------------------------------------------------------------------

#define ACT_NONE 0
#define ACT_LRELU 1

typedef __attribute__((ext_vector_type(8))) short short8;
typedef __attribute__((ext_vector_type(4))) float floatx4;

__device__ __forceinline__ ushort f2b(float x) {
    union { float f; unsigned u; } v; v.f = x;
    return (ushort)((v.u + 0x7fffu + ((v.u >> 16) & 1u)) >> 16);
}
__device__ __forceinline__ float b2f(ushort b) {
    union { unsigned u; float f; } v; v.u = ((unsigned)b) << 16;
    return v.f;
}
__device__ __forceinline__ void gload16(const ushort* g, ushort* l) {
    __builtin_amdgcn_global_load_lds(
        (const __attribute__((address_space(1))) void*)g,
        (__attribute__((address_space(3))) void*)l, 16, 0, 0);
}

// ---------------- fused relation-table GEMM prep (z selects output) ----------------
__global__ __launch_bounds__(256) void relprep_k(
    const float* __restrict__ A, const float* __restrict__ B0,
    const float* __restrict__ B1, const float* __restrict__ B2,
    float* __restrict__ C0, float* __restrict__ C1, ushort* __restrict__ C2,
    int M, int N, int K)
{
    __shared__ float As[16][68];
    __shared__ float Bs[16][68];
    const int z = blockIdx.z;
    const float* B = (z == 0) ? B0 : (z == 1) ? B1 : B2;
    const int tid = threadIdx.x;
    const int tx = tid & 15, ty = tid >> 4;
    const int m0 = blockIdx.x * 64, n0 = blockIdx.y * 64;
    float acc[4][4] = {};
    const int ar  = tid >> 2;
    const int ac4 = (tid & 3) * 4;
    const int brow = tid >> 4;
    const int bc4  = (tid & 15) * 4;
    const int gm = m0 + ar;
    const float* Arow = (gm < M) ? (A + (size_t)gm * K) : nullptr;
    for (int k0 = 0; k0 < K; k0 += 16) {
        float4 av = make_float4(0.f, 0.f, 0.f, 0.f);
        if (Arow) av = *(const float4*)(Arow + k0 + ac4);
        As[ac4 + 0][ar] = av.x;
        As[ac4 + 1][ar] = av.y;
        As[ac4 + 2][ar] = av.z;
        As[ac4 + 3][ar] = av.w;
        float4 bv = *(const float4*)(B + (size_t)(k0 + brow) * N + n0 + bc4);
        *(float4*)&Bs[brow][bc4] = bv;
        __syncthreads();
        #pragma unroll
        for (int kk = 0; kk < 16; ++kk) {
            float4 a4 = *(float4*)&As[kk][ty << 2];
            float4 b4 = *(float4*)&Bs[kk][tx << 2];
            float avr[4] = {a4.x, a4.y, a4.z, a4.w};
            float bvr[4] = {b4.x, b4.y, b4.z, b4.w};
            #pragma unroll
            for (int i = 0; i < 4; ++i)
                #pragma unroll
                for (int j = 0; j < 4; ++j)
                    acc[i][j] = fmaf(avr[i], bvr[j], acc[i][j]);
        }
        __syncthreads();
    }
    const int n = n0 + (tx << 2);
    #pragma unroll
    for (int i = 0; i < 4; ++i) {
        int m = m0 + (ty << 2) + i;
        if (m >= M) continue;
        if (z == 2) {
            ushort4 u;
            u.x = f2b(acc[i][0]); u.y = f2b(acc[i][1]);
            u.z = f2b(acc[i][2]); u.w = f2b(acc[i][3]);
            *(ushort4*)(C2 + (size_t)m * N + n) = u;
        } else {
            float* C = (z == 0) ? C0 : C1;
            *(float4*)(C + (size_t)m * N + n) =
                make_float4(acc[i][0], acc[i][1], acc[i][2], acc[i][3]);
        }
    }
}

// ---------------- weight prep ----------------
__global__ __launch_bounds__(256) void convert16_k(
    const float* __restrict__ in, ushort* __restrict__ out, int n)
{
    int i = blockIdx.x * 256 + threadIdx.x;
    if (i < n) out[i] = f2b(in[i]);
}
// W_ih and W_hh in one launch (each 768*256)
__global__ __launch_bounds__(256) void convertW_k(
    const float* __restrict__ a, const float* __restrict__ b,
    ushort* __restrict__ oa, ushort* __restrict__ ob)
{
    int i = blockIdx.x * 256 + threadIdx.x;
    const int n = 768 * 256;
    if (i < n) oa[i] = f2b(a[i]);
    else       ob[i - n] = f2b(b[i - n]);
}
// 4 weight transposes in one launch; blockIdx.y selects target.
__global__ __launch_bounds__(256) void transpose4_k(
    const float* __restrict__ Ws, const float* __restrict__ We2h,
    const float* __restrict__ candW,
    ushort* __restrict__ WsT, ushort* __restrict__ We2hT,
    ushort* __restrict__ c1T, ushort* __restrict__ c3T)
{
    const int y = blockIdx.y;
    const float* in; ushort* out; int k0, KS;
    const int N = 256;
    if (y == 0)      { in = Ws;    out = WsT;   k0 = 0;   KS = 256; }
    else if (y == 1) { in = We2h;  out = We2hT; k0 = 0;   KS = 128; }
    else if (y == 2) { in = candW; out = c1T;   k0 = 0;   KS = 128; }
    else             { in = candW; out = c3T;   k0 = 256; KS = 256; }
    int i = blockIdx.x * 256 + threadIdx.x;
    if (i >= KS * N) return;
    int k = i / N, n = i - k * N;
    out[(size_t)n * KS + k] = f2b(in[(size_t)(k0 + k) * N + n]);
}

// ---------------- pipelined bf16-A MFMA GEMM (steps 5/6) ----------------
__global__ __launch_bounds__(256) void gemm16p_k(
    const ushort* __restrict__ A16, const int* __restrict__ a_idx,
    const ushort* __restrict__ BT, const float* __restrict__ bias,
    float* __restrict__ C, ushort* __restrict__ C16,
    int M, int N, int K, int act)
{
    __shared__ ushort As[2][128 * 32];
    __shared__ ushort Bs[2][128 * 32];
    const int tid = threadIdx.x;
    const int l = tid & 63, w = tid >> 6;
    const int m0 = blockIdx.y * 128, n0 = blockIdx.x * 128;

    const ushort* agp[2];
    const ushort* bgp[2];
    #pragma unroll
    for (int j = 0; j < 2; ++j) {
        int row = j * 64 + w * 16 + (l >> 2);
        int seg = (l & 3) ^ (row & 3);
        int r = m0 + row; if (r >= M) r = M - 1;
        int rr = a_idx ? a_idx[r] : r;
        agp[j] = A16 + (size_t)rr * K + seg * 8;
        bgp[j] = BT + (size_t)(n0 + row) * K + seg * 8;
    }

    const int wm = (w & 1) * 64, wn = (w >> 1) * 64;
    const int cl = l & 15, q = l >> 4;
    const int sseg = (q ^ (cl & 3)) * 8;
    const int aoff = (wm + cl) * 32 + sseg;
    const int boff = (wn + cl) * 32 + sseg;

    floatx4 acc[4][4];
    #pragma unroll
    for (int mi = 0; mi < 4; ++mi)
        #pragma unroll
        for (int ni = 0; ni < 4; ++ni) acc[mi][ni] = 0.f;

    const int NT = K >> 5;
    #pragma unroll
    for (int j = 0; j < 2; ++j) {
        gload16(agp[j], &As[0][j * 2048 + w * 512]);
        gload16(bgp[j], &Bs[0][j * 2048 + w * 512]);
    }
    __syncthreads();

    int buf = 0;
    for (int t = 0; t < NT; ++t) {
        if (t + 1 < NT) {
            int k0 = (t + 1) * 32;
            #pragma unroll
            for (int j = 0; j < 2; ++j) {
                gload16(agp[j] + k0, &As[buf ^ 1][j * 2048 + w * 512]);
                gload16(bgp[j] + k0, &Bs[buf ^ 1][j * 2048 + w * 512]);
            }
        }
        short8 af[4], bf[4];
        #pragma unroll
        for (int mi = 0; mi < 4; ++mi) af[mi] = *(short8*)&As[buf][aoff + mi * 512];
        #pragma unroll
        for (int ni = 0; ni < 4; ++ni) bf[ni] = *(short8*)&Bs[buf][boff + ni * 512];
        #pragma unroll
        for (int mi = 0; mi < 4; ++mi)
            #pragma unroll
            for (int ni = 0; ni < 4; ++ni)
                acc[mi][ni] = __builtin_amdgcn_mfma_f32_16x16x32_bf16(
                    bf[ni], af[mi], acc[mi][ni], 0, 0, 0);
        __syncthreads();
        buf ^= 1;
    }

    #pragma unroll
    for (int mi = 0; mi < 4; ++mi) {
        int row = m0 + wm + mi * 16 + cl;
        if (row >= M) continue;
        #pragma unroll
        for (int ni = 0; ni < 4; ++ni) {
            int col = n0 + wn + ni * 16 + q * 4;
            float4 bv = bias ? *(const float4*)(bias + col)
                             : make_float4(0.f, 0.f, 0.f, 0.f);
            float v[4];
            #pragma unroll
            for (int r = 0; r < 4; ++r) {
                float x = acc[mi][ni][r] + ((const float*)&bv)[r];
                if (act == ACT_LRELU) x = x > 0.f ? x : 0.01f * x;
                v[r] = x;
            }
            if (C16) {
                ushort4 u;
                u.x = f2b(v[0]); u.y = f2b(v[1]); u.z = f2b(v[2]); u.w = f2b(v[3]);
                *(ushort4*)(C16 + (size_t)row * N + col) = u;
            }
            if (C) *(float4*)(C + (size_t)row * N + col) =
                       make_float4(v[0], v[1], v[2], v[3]);
        }
    }
}

// ---------------- wide fp32-A MFMA GEMM: 64x256 block, A read once (step 2) ----------------
__global__ __launch_bounds__(256) void gemm16pw_k(
    const float* __restrict__ A, const ushort* __restrict__ BT,
    const float* __restrict__ bias, ushort* __restrict__ C16,
    int M, int K, int act)      // N fixed = 256
{
    __shared__ ushort As[2][64 * 36];
    __shared__ ushort Bs[2][256 * 32];
    const int tid = threadIdx.x;
    const int l = tid & 63, w = tid >> 6;
    const int m0 = blockIdx.x * 64;

    const int ar = tid >> 2, af4 = tid & 3;
    int rr = m0 + ar; if (rr >= M) rr = M - 1;
    const float* agp = A + (size_t)rr * K + af4 * 8;
    const int awadr = ar * 36 + af4 * 8;

    const ushort* bgp[4];
    #pragma unroll
    for (int j = 0; j < 4; ++j) {
        int row = j * 64 + w * 16 + (l >> 2);
        int seg = (l & 3) ^ (row & 3);
        bgp[j] = BT + (size_t)row * K + seg * 8;
    }

    const int cl = l & 15, q = l >> 4;
    const int aoff = cl * 36 + q * 8;
    const int boff = (w * 64 + cl) * 32 + (q ^ (cl & 3)) * 8;

    floatx4 acc[4][4];
    #pragma unroll
    for (int mi = 0; mi < 4; ++mi)
        #pragma unroll
        for (int ni = 0; ni < 4; ++ni) acc[mi][ni] = 0.f;

    const int NT = K >> 5;
    #pragma unroll
    for (int j = 0; j < 4; ++j)
        gload16(bgp[j], &Bs[0][j * 2048 + w * 512]);
    {
        float4 v0 = *(const float4*)(agp);
        float4 v1 = *(const float4*)(agp + 4);
        ushort4 u0, u1;
        u0.x = f2b(v0.x); u0.y = f2b(v0.y); u0.z = f2b(v0.z); u0.w = f2b(v0.w);
        u1.x = f2b(v1.x); u1.y = f2b(v1.y); u1.z = f2b(v1.z); u1.w = f2b(v1.w);
        *(ushort4*)&As[0][awadr] = u0;
        *(ushort4*)&As[0][awadr + 4] = u1;
    }
    __syncthreads();

    int buf = 0;
    for (int t = 0; t < NT; ++t) {
        float4 v0, v1;
        if (t + 1 < NT) {
            int k0 = (t + 1) * 32;
            #pragma unroll
            for (int j = 0; j < 4; ++j)
                gload16(bgp[j] + k0, &Bs[buf ^ 1][j * 2048 + w * 512]);
            v0 = *(const float4*)(agp + k0);
            v1 = *(const float4*)(agp + k0 + 4);
        }
        short8 bf[4];
        #pragma unroll
        for (int ni = 0; ni < 4; ++ni) bf[ni] = *(short8*)&Bs[buf][boff + ni * 512];
        #pragma unroll
        for (int mi = 0; mi < 4; ++mi) {
            short8 af = *(short8*)&As[buf][aoff + mi * 576];
            #pragma unroll
            for (int ni = 0; ni < 4; ++ni)
                acc[mi][ni] = __builtin_amdgcn_mfma_f32_16x16x32_bf16(
                    bf[ni], af, acc[mi][ni], 0, 0, 0);
        }
        if (t + 1 < NT) {
            ushort4 u0, u1;
            u0.x = f2b(v0.x); u0.y = f2b(v0.y); u0.z = f2b(v0.z); u0.w = f2b(v0.w);
            u1.x = f2b(v1.x); u1.y = f2b(v1.y); u1.z = f2b(v1.z); u1.w = f2b(v1.w);
            *(ushort4*)&As[buf ^ 1][awadr] = u0;
            *(ushort4*)&As[buf ^ 1][awadr + 4] = u1;
        }
        __syncthreads();
        buf ^= 1;
    }

    #pragma unroll
    for (int mi = 0; mi < 4; ++mi) {
        int row = m0 + mi * 16 + cl;
        if (row >= M) continue;
        #pragma unroll
        for (int ni = 0; ni < 4; ++ni) {
            int col = w * 64 + ni * 16 + q * 4;
            float4 bv = bias ? *(const float4*)(bias + col)
                             : make_float4(0.f, 0.f, 0.f, 0.f);
            ushort4 u;
            float x0 = acc[mi][ni][0] + bv.x;
            float x1 = acc[mi][ni][1] + bv.y;
            float x2 = acc[mi][ni][2] + bv.z;
            float x3 = acc[mi][ni][3] + bv.w;
            if (act == ACT_LRELU) {
                x0 = x0 > 0.f ? x0 : 0.01f * x0;
                x1 = x1 > 0.f ? x1 : 0.01f * x1;
                x2 = x2 > 0.f ? x2 : 0.01f * x2;
                x3 = x3 > 0.f ? x3 : 0.01f * x3;
            }
            u.x = f2b(x0); u.y = f2b(x1); u.z = f2b(x2); u.w = f2b(x3);
            *(ushort4*)(C16 + (size_t)row * 256 + col) = u;
        }
    }
}

// ---------------- qdot[b] = query_repr[b] . rank_W[256:512] ----------------
__global__ __launch_bounds__(256) void qdot_k(
    const float* __restrict__ q, const float* __restrict__ rank_W,
    float* __restrict__ qdot)
{
    int b = blockIdx.x * 4 + (threadIdx.x >> 6);
    int l = threadIdx.x & 63;
    float s = 0.f;
    #pragma unroll
    for (int k = 0; k < 4; ++k) {
        int h = l + k * 64;
        s += q[(size_t)b * 256 + h] * rank_W[256 + h];
    }
    #pragma unroll
    for (int off = 32; off; off >>= 1) s += __shfl_xor(s, off, 64);
    if (l == 0) qdot[b] = s;
}

// ---------------- per-edge attention alpha, head-sorted order ----------------
__global__ __launch_bounds__(256) void alpha_k(
    const ushort* __restrict__ nodeWs16, const float* __restrict__ relWr,
    const float* __restrict__ relWqr, const float* __restrict__ bqr,
    const float* __restrict__ w_alpha, const float* __restrict__ b_alpha_p,
    const int* __restrict__ hcsr_hn, const int* __restrict__ hcsr_er,
    const int* __restrict__ hcsr_qr, const int* __restrict__ hcsr_e,
    float* __restrict__ alpha_out)
{
    const int tid = threadIdx.x;
    const int e0 = blockIdx.x * 32;
    __shared__ int hn[32], er[32], qr[32], se[32];
    if (tid < 32) {
        int i = e0 + tid;
        hn[tid] = hcsr_hn[i]; er[tid] = hcsr_er[i];
        qr[tid] = hcsr_qr[i]; se[tid] = hcsr_e[i];
    }
    __syncthreads();
    const int tx = tid & 63, ty = tid >> 6;
    const int c = tx * 4;
    const float4 bq = *(const float4*)(bqr + c);
    const float4 wa = *(const float4*)(w_alpha + c);
    float part[8];
    #pragma unroll
    for (int i2 = 0; i2 < 8; ++i2) {
        int i = ty * 8 + i2;
        ushort4 a16 = *(const ushort4*)(nodeWs16 + (size_t)hn[i] * 256 + c);
        float4 b = *(const float4*)(relWr + (size_t)er[i] * 256 + c);
        float4 d = *(const float4*)(relWqr + (size_t)qr[i] * 256 + c);
        float x0 = fmaxf(b2f(a16.x) + b.x + d.x + bq.x, 0.f);
        float x1 = fmaxf(b2f(a16.y) + b.y + d.y + bq.y, 0.f);
        float x2 = fmaxf(b2f(a16.z) + b.z + d.z + bq.z, 0.f);
        float x3 = fmaxf(b2f(a16.w) + b.w + d.w + bq.w, 0.f);
        part[i2] = x0 * wa.x + x1 * wa.y + x2 * wa.z + x3 * wa.w;
    }
    #pragma unroll
    for (int off = 32; off; off >>= 1)
        #pragma unroll
        for (int i2 = 0; i2 < 8; ++i2)
            part[i2] += __shfl_xor(part[i2], off, 64);
    if (tx == 0) {
        float ba = b_alpha_p[0];
        #pragma unroll
        for (int i2 = 0; i2 < 8; ++i2)
            alpha_out[se[ty * 8 + i2]] = 1.f / (1.f + __expf(-(part[i2] + ba)));
    }
}

// ---------------- CSR build ----------------
__global__ __launch_bounds__(256) void hist2_k(
    const int* __restrict__ tail_node, const int* __restrict__ head_node,
    int* __restrict__ deg_t, int* __restrict__ deg_h, int M)
{
    int e = blockIdx.x * 256 + threadIdx.x;
    if (e < M) {
        atomicAdd(&deg_t[tail_node[e]], 1);
        atomicAdd(&deg_h[head_node[e]], 1);
    }
}
__global__ __launch_bounds__(512) void scan1_k(
    const int* __restrict__ deg, int* __restrict__ partial, int N)
{
    __shared__ int sm[512];
    int i = blockIdx.x * 512 + threadIdx.x;
    sm[threadIdx.x] = (i < N) ? deg[i] : 0;
    __syncthreads();
    for (int off = 256; off; off >>= 1) {
        if (threadIdx.x < off) sm[threadIdx.x] += sm[threadIdx.x + off];
        __syncthreads();
    }
    if (threadIdx.x == 0) partial[blockIdx.x] = sm[0];
}
__global__ __launch_bounds__(256) void scan2_k(
    int* __restrict__ partial, int nPart, int* __restrict__ offsets, int N, int M)
{
    __shared__ int sm[256];
    int t = threadIdx.x;
    int v = (t < nPart) ? partial[t] : 0;
    sm[t] = v;
    __syncthreads();
    for (int off = 1; off < 256; off <<= 1) {
        int add = (t >= off) ? sm[t - off] : 0;
        __syncthreads();
        sm[t] += add;
        __syncthreads();
    }
    if (t < nPart) partial[t] = sm[t] - v;
    if (t == 0) offsets[N] = M;
}
__global__ __launch_bounds__(512) void scan3_k(
    const int* __restrict__ deg, const int* __restrict__ partial,
    int* __restrict__ offsets, int* __restrict__ cursor, int N)
{
    __shared__ int sm[512];
    int i = blockIdx.x * 512 + threadIdx.x;
    int t = threadIdx.x;
    int v = (i < N) ? deg[i] : 0;
    sm[t] = v;
    __syncthreads();
    for (int off = 1; off < 512; off <<= 1) {
        int add = (t >= off) ? sm[t - off] : 0;
        __syncthreads();
        sm[t] += add;
        __syncthreads();
    }
    if (i < N) {
        int excl = partial[blockIdx.x] + sm[t] - v;
        offsets[i] = excl;
        cursor[i] = excl;
    }
}
__global__ __launch_bounds__(256) void fill_k(
    const int* __restrict__ tail_node, const int* __restrict__ tail_ent,
    const int* __restrict__ edge_rel, const int* __restrict__ batch_idx,
    int* __restrict__ cursor, int* __restrict__ ce, int* __restrict__ cte,
    int* __restrict__ cer, int* __restrict__ ctn, int* __restrict__ cbi, int M)
{
    int e = blockIdx.x * 256 + threadIdx.x;
    if (e < M) {
        int tn = tail_node[e];
        int pos = atomicAdd(&cursor[tn], 1);
        ce[pos] = e; cte[pos] = tail_ent[e]; cer[pos] = edge_rel[e];
        ctn[pos] = tn; cbi[pos] = batch_idx[e];
    }
}
__global__ __launch_bounds__(256) void hfill_k(
    const int* __restrict__ head_node, const int* __restrict__ edge_rel,
    const int* __restrict__ query_rel, int* __restrict__ cursor,
    int* __restrict__ hhn, int* __restrict__ her, int* __restrict__ hqr,
    int* __restrict__ he, int M)
{
    int e = blockIdx.x * 256 + threadIdx.x;
    if (e < M) {
        int h = head_node[e];
        int pos = atomicAdd(&cursor[h], 1);
        hhn[pos] = h; her[pos] = edge_rel[e]; hqr[pos] = query_rel[e]; he[pos] = e;
    }
}

// ---------------- segment-sum via CSR gather-reduce (2-edge unroll) ----------------
__global__ __launch_bounds__(256) void agg_csr_k(
    const float* __restrict__ relation_emb, const ushort* __restrict__ ent16,
    const float* __restrict__ alpha, const int* __restrict__ csr_e,
    const int* __restrict__ csr_er, const int* __restrict__ csr_te,
    const int* __restrict__ offsets, ushort* __restrict__ agg16)
{
    int node = blockIdx.x * 4 + (threadIdx.x >> 6);
    int lane = threadIdx.x & 63;
    int beg = offsets[node], end = offsets[node + 1];
    float4 acc = make_float4(0.f, 0.f, 0.f, 0.f);
    const int c = lane * 4;
    int j = beg;
    for (; j + 1 < end; j += 2) {
        float a0 = alpha[csr_e[j]];
        float a1 = alpha[csr_e[j + 1]];
        float4 v0, v1;
        if (lane < 32) {
            v0 = *(const float4*)(relation_emb + (size_t)csr_er[j] * 128 + c);
            v1 = *(const float4*)(relation_emb + (size_t)csr_er[j + 1] * 128 + c);
        } else {
            ushort4 u0 = *(const ushort4*)(ent16 + (size_t)csr_te[j] * 128 + (c - 128));
            ushort4 u1 = *(const ushort4*)(ent16 + (size_t)csr_te[j + 1] * 128 + (c - 128));
            v0 = make_float4(b2f(u0.x), b2f(u0.y), b2f(u0.z), b2f(u0.w));
            v1 = make_float4(b2f(u1.x), b2f(u1.y), b2f(u1.z), b2f(u1.w));
        }
        acc.x += v0.x * a0 + v1.x * a1;
        acc.y += v0.y * a0 + v1.y * a1;
        acc.z += v0.z * a0 + v1.z * a1;
        acc.w += v0.w * a0 + v1.w * a1;
    }
    if (j < end) {
        float a = alpha[csr_e[j]];
        float4 v;
        if (lane < 32) {
            v = *(const float4*)(relation_emb + (size_t)csr_er[j] * 128 + c);
        } else {
            ushort4 u = *(const ushort4*)(ent16 + (size_t)csr_te[j] * 128 + (c - 128));
            v = make_float4(b2f(u.x), b2f(u.y), b2f(u.z), b2f(u.w));
        }
        acc.x += v.x * a; acc.y += v.y * a;
        acc.z += v.z * a; acc.w += v.w * a;
    }
    ushort4 o;
    o.x = f2b(acc.x); o.y = f2b(acc.y); o.z = f2b(acc.z); o.w = f2b(acc.w);
    *(ushort4*)(agg16 + (size_t)node * 256 + c) = o;
}

// ---------------- fused GRU + LayerNorm + (h_new @ candW3 + cand_b) ----------------
// 64 rows/block. Phase 1: per-row GRU+LN into LDS tile (stride 264, 2-way banks).
// Phase 2: MFMA 64x256 tile @ candW3T (B from L2), write hnewCand16.
__global__ __launch_bounds__(256) void gruln_cand_k(
    const ushort* __restrict__ gx, const ushort* __restrict__ gh,
    const ushort* __restrict__ h_prev, const float* __restrict__ ln_g,
    const float* __restrict__ ln_b, const float* __restrict__ cand_b,
    const ushort* __restrict__ candW3T, ushort* __restrict__ hnewCand16,
    int n0, int NC)
{
    __shared__ ushort Hs[64 * 264];
    const int tid = threadIdx.x;
    const int l = tid & 63, w = tid >> 6;
    const int r0 = blockIdx.x * 64;

    // ---- phase 1: GRU + LN, 16 passes, wave handles one row per pass ----
    const float4 lg = *(const float4*)(ln_g + l * 4);
    const float4 lb = *(const float4*)(ln_b + l * 4);
    for (int p = 0; p < 16; ++p) {
        int row = p * 4 + w;
        int nl = r0 + row; if (nl >= NC) nl = NC - 1;
        const ushort* gxr = gx + (size_t)nl * 768;
        const ushort* ghr = gh + (size_t)nl * 768;
        const ushort* hpr = h_prev + (size_t)(n0 + nl) * 256;
        ushort4 xr4 = *(const ushort4*)(gxr + l * 4);
        ushort4 xz4 = *(const ushort4*)(gxr + 256 + l * 4);
        ushort4 xn4 = *(const ushort4*)(gxr + 512 + l * 4);
        ushort4 hr4 = *(const ushort4*)(ghr + l * 4);
        ushort4 hz4 = *(const ushort4*)(ghr + 256 + l * 4);
        ushort4 hn4 = *(const ushort4*)(ghr + 512 + l * 4);
        ushort4 hp4 = *(const ushort4*)(hpr + l * 4);
        float hv[4]; float s = 0.f, s2 = 0.f;
        #pragma unroll
        for (int t = 0; t < 4; ++t) {
            float xr = b2f(((const ushort*)&xr4)[t]);
            float xz = b2f(((const ushort*)&xz4)[t]);
            float xn = b2f(((const ushort*)&xn4)[t]);
            float hr_ = b2f(((const ushort*)&hr4)[t]);
            float hz_ = b2f(((const ushort*)&hz4)[t]);
            float hn_ = b2f(((const ushort*)&hn4)[t]);
            float hp = b2f(((const ushort*)&hp4)[t]);
            float r = 1.f / (1.f + __expf(-(xr + hr_)));
            float z = 1.f / (1.f + __expf(-(xz + hz_)));
            float nn = tanhf(xn + r * hn_);
            float v = (1.f - z) * nn + z * hp;
            hv[t] = v; s += v; s2 += v * v;
        }
        #pragma unroll
        for (int off = 32; off; off >>= 1) {
            s  += __shfl_xor(s, off, 64);
            s2 += __shfl_xor(s2, off, 64);
        }
        float mean = s * (1.f / 256.f);
        float var  = s2 * (1.f / 256.f) - mean * mean;
        float rstd = rsqrtf(var + 1e-5f);
        ushort4 o;
        o.x = f2b((hv[0] - mean) * rstd * lg.x + lb.x);
        o.y = f2b((hv[1] - mean) * rstd * lg.y + lb.y);
        o.z = f2b((hv[2] - mean) * rstd * lg.z + lb.z);
        o.w = f2b((hv[3] - mean) * rstd * lg.w + lb.w);
        *(ushort4*)&Hs[row * 264 + l * 4] = o;
    }
    __syncthreads();

    // ---- phase 2: 64x256 MFMA vs candW3T [256][256] ----
    const int cl = l & 15, q = l >> 4;
    floatx4 acc[4][4];
    #pragma unroll
    for (int mi = 0; mi < 4; ++mi)
        #pragma unroll
        for (int ni = 0; ni < 4; ++ni) acc[mi][ni] = 0.f;

    const ushort* bbase = candW3T + (size_t)(w * 64 + cl) * 256 + q * 8;
    for (int k0 = 0; k0 < 256; k0 += 32) {
        short8 af[4], bf[4];
        #pragma unroll
        for (int ni = 0; ni < 4; ++ni)
            bf[ni] = *(const short8*)(bbase + ni * 4096 + k0);
        #pragma unroll
        for (int mi = 0; mi < 4; ++mi)
            af[mi] = *(short8*)&Hs[(mi * 16 + cl) * 264 + k0 + q * 8];
        #pragma unroll
        for (int mi = 0; mi < 4; ++mi)
            #pragma unroll
            for (int ni = 0; ni < 4; ++ni)
                acc[mi][ni] = __builtin_amdgcn_mfma_f32_16x16x32_bf16(
                    bf[ni], af[mi], acc[mi][ni], 0, 0, 0);
    }
    #pragma unroll
    for (int mi = 0; mi < 4; ++mi) {
        int gr = r0 + mi * 16 + cl;
        if (gr >= NC) continue;
        #pragma unroll
        for (int ni = 0; ni < 4; ++ni) {
            int col = w * 64 + ni * 16 + q * 4;
            float4 bv = *(const float4*)(cand_b + col);
            ushort4 u;
            u.x = f2b(acc[mi][ni][0] + bv.x);
            u.y = f2b(acc[mi][ni][1] + bv.y);
            u.z = f2b(acc[mi][ni][2] + bv.z);
            u.w = f2b(acc[mi][ni][3] + bv.w);
            *(ushort4*)(hnewCand16 + (size_t)(n0 + gr) * 256 + col) = u;
        }
    }
}

// ---------------- fused score v3.1: no index-LDS, epilogue gather prefetch ----------------
__global__ __launch_bounds__(256) void score_mfma_k(
    const ushort* __restrict__ ent16, const ushort* __restrict__ candW1T,
    const ushort* __restrict__ relCand16, const ushort* __restrict__ hnewCand16,
    const float* __restrict__ rank_W, const float* __restrict__ rank_b_p,
    const float* __restrict__ qdot,
    const int* __restrict__ csr_e, const int* __restrict__ csr_te,
    const int* __restrict__ csr_er, const int* __restrict__ csr_tn,
    const int* __restrict__ csr_bi, float* __restrict__ scores)
{
    __shared__ ushort As[64 * 136];
    __shared__ float s_part[4][64];
    const int tid = threadIdx.x;
    const int e0 = blockIdx.x * 64;
    const int l = tid & 63, w = tid >> 6;
    const int cl = l & 15, q = l >> 4;

    // stage A (pre-barrier): 4 threads/row x 4 segs; te loaded directly
    {
        const int row = tid >> 2, s0 = tid & 3;
        const ushort* ar = ent16 + (size_t)csr_te[e0 + row] * 128;
        #pragma unroll
        for (int j = 0; j < 4; ++j) {
            int seg = s0 + j * 4;
            *(uint4*)&As[row * 136 + seg * 8] = *(const uint4*)(ar + seg * 8);
        }
    }
    // per-lane epilogue indices (coalesced) + prefetch batch 0
    int er[4], tn[4];
    #pragma unroll
    for (int mi = 0; mi < 4; ++mi) {
        int row = mi * 16 + cl;
        er[mi] = csr_er[e0 + row];
        tn[mi] = csr_tn[e0 + row];
    }
    ushort4 rc[2][4], hc[2][4];
    #pragma unroll
    for (int ni = 0; ni < 4; ++ni) {
        int col = w * 64 + ni * 16 + q * 4;
        rc[0][ni] = *(const ushort4*)(relCand16 + (size_t)er[0] * 256 + col);
        hc[0][ni] = *(const ushort4*)(hnewCand16 + (size_t)tn[0] * 256 + col);
    }
    __syncthreads();

    floatx4 acc[4][4];
    #pragma unroll
    for (int mi = 0; mi < 4; ++mi)
        #pragma unroll
        for (int ni = 0; ni < 4; ++ni) acc[mi][ni] = 0.f;

    const ushort* bbase = candW1T + (size_t)(w * 64 + cl) * 128 + q * 8;
    for (int k0 = 0; k0 < 128; k0 += 32) {
        short8 af[4], bf[4];
        #pragma unroll
        for (int ni = 0; ni < 4; ++ni)
            bf[ni] = *(const short8*)(bbase + ni * 2048 + k0);
        #pragma unroll
        for (int mi = 0; mi < 4; ++mi)
            af[mi] = *(short8*)&As[(mi * 16 + cl) * 136 + k0 + q * 8];
        #pragma unroll
        for (int mi = 0; mi < 4; ++mi)
            #pragma unroll
            for (int ni = 0; ni < 4; ++ni)
                acc[mi][ni] = __builtin_amdgcn_mfma_f32_16x16x32_bf16(
                    bf[ni], af[mi], acc[mi][ni], 0, 0, 0);
    }

    // epilogue: ring prefetch (slot mi&1), rank_W hoisted
    float4 rw[4];
    #pragma unroll
    for (int ni = 0; ni < 4; ++ni)
        rw[ni] = *(const float4*)(rank_W + w * 64 + ni * 16 + q * 4);

    float rowsum[4];
    #pragma unroll
    for (int mi = 0; mi < 4; ++mi) {
        if (mi < 3) {
            int p = (mi + 1) & 1;
            #pragma unroll
            for (int ni = 0; ni < 4; ++ni) {
                int col = w * 64 + ni * 16 + q * 4;
                rc[p][ni] = *(const ushort4*)(relCand16 + (size_t)er[mi + 1] * 256 + col);
                hc[p][ni] = *(const ushort4*)(hnewCand16 + (size_t)tn[mi + 1] * 256 + col);
            }
        }
        const int p = mi & 1;
        float rs = 0.f;
        #pragma unroll
        for (int ni = 0; ni < 4; ++ni) {
            float v0 = acc[mi][ni][0] + b2f(rc[p][ni].x) + b2f(hc[p][ni].x);
            float v1 = acc[mi][ni][1] + b2f(rc[p][ni].y) + b2f(hc[p][ni].y);
            float v2 = acc[mi][ni][2] + b2f(rc[p][ni].z) + b2f(hc[p][ni].z);
            float v3 = acc[mi][ni][3] + b2f(rc[p][ni].w) + b2f(hc[p][ni].w);
            v0 = v0 > 0.f ? v0 : 0.01f * v0;
            v1 = v1 > 0.f ? v1 : 0.01f * v1;
            v2 = v2 > 0.f ? v2 : 0.01f * v2;
            v3 = v3 > 0.f ? v3 : 0.01f * v3;
            rs += v0 * rw[ni].x + v1 * rw[ni].y + v2 * rw[ni].z + v3 * rw[ni].w;
        }
        rowsum[mi] = rs;
    }
    #pragma unroll
    for (int mi = 0; mi < 4; ++mi) {
        rowsum[mi] += __shfl_xor(rowsum[mi], 16, 64);
        rowsum[mi] += __shfl_xor(rowsum[mi], 32, 64);
    }
    if (q == 0) {
        #pragma unroll
        for (int mi = 0; mi < 4; ++mi)
            s_part[w][mi * 16 + cl] = rowsum[mi];
    }
    __syncthreads();
    if (tid < 64) {
        int idx = e0 + tid;
        float s = s_part[0][tid] + s_part[1][tid] + s_part[2][tid] + s_part[3][tid]
                + qdot[csr_bi[idx]] + rank_b_p[0];
        scores[csr_e[idx]] = s;
    }
}

// ---------------------------------------------------------------------------
extern "C" void kernel_launch(void* const* d_in, const int* in_sizes, int n_in,
                              void* d_out, int out_size, void* d_ws, size_t ws_size,
                              hipStream_t stream)
{
    const float* entity_emb   = (const float*)d_in[0];
    const float* relation_emb = (const float*)d_in[1];
    const float* node_hidden  = (const float*)d_in[2];
    const float* query_repr   = (const float*)d_in[3];
    const float* Ws    = (const float*)d_in[4];
    const float* Wr    = (const float*)d_in[5];
    const float* Wqr   = (const float*)d_in[6];
    const float* bqr   = (const float*)d_in[7];
    const float* w_alpha = (const float*)d_in[8];
    const float* b_alpha = (const float*)d_in[9];
    const float* W_ih  = (const float*)d_in[10];
    const float* W_hh  = (const float*)d_in[11];
    const float* b_ih  = (const float*)d_in[12];
    const float* b_hh  = (const float*)d_in[13];
    const float* We2h_W = (const float*)d_in[14];
    const float* We2h_b = (const float*)d_in[15];
    const float* cand_W = (const float*)d_in[16];
    const float* cand_b = (const float*)d_in[17];
    const float* rank_W = (const float*)d_in[18];
    const float* rank_b = (const float*)d_in[19];
    const float* ln_g  = (const float*)d_in[20];
    const float* ln_b  = (const float*)d_in[21];
    const int* head_node = (const int*)d_in[22];
    const int* edge_rel  = (const int*)d_in[23];
    const int* tail_ent  = (const int*)d_in[24];
    const int* tail_node = (const int*)d_in[25];
    const int* query_rel = (const int*)d_in[26];
    const int* batch_idx = (const int*)d_in[27];
    const int* tail_node_ent = (const int*)d_in[28];
    float* out = (float*)d_out;
    (void)in_sizes; (void)n_in; (void)out_size; (void)ws_size;

    const int M = 200000, NNEW = 50000, NNODES = 100000, NREL = 500;
    const int NENT = 200000, E = 128;
    const int NCHUNK = 2, NC = NNEW / NCHUNK;   // 25000
    const int NP_T = (NNEW + 511) / 512;        // 98
    const int NP_H = (NNODES + 511) / 512;      // 196

    // ---- workspace layout (float units) ----
    float* w = (float*)d_ws;
    float* relWr    = w; w += NREL * 256;
    float* relWqr   = w; w += NREL * 256;
    float* qdot     = w; w += 256;
    float* alpha    = w; w += M;
    // bf16 tables (16B-aligned bases)
    ushort* h_prev16   = (ushort*)w; w += (size_t)NNEW * 256 / 2;
    ushort* agg16      = (ushort*)w; w += (size_t)NNEW * 256 / 2;
    ushort* hnewCand16 = (ushort*)w; w += (size_t)NNEW * 256 / 2;
    ushort* relCand16  = (ushort*)w; w += (NREL * 256) / 2;
    ushort* ent16      = (ushort*)w; w += (size_t)NENT * E / 2;
    // bf16 weights
    ushort* W_ih16    = (ushort*)w; w += (768 * 256) / 2;
    ushort* W_hh16    = (ushort*)w; w += (768 * 256) / 2;
    ushort* WsT16     = (ushort*)w; w += (256 * 256) / 2;
    ushort* We2hT16   = (ushort*)w; w += (256 * 128) / 2;
    ushort* candW1T16 = (ushort*)w; w += (256 * 128) / 2;
    ushort* candW3T16 = (ushort*)w; w += (256 * 256) / 2;
    // ints
    int* deg      = (int*)w; w += NNEW;
    int* offsets  = (int*)w; w += NNEW + 1;
    int* cursor   = (int*)w; w += NNEW;
    int* deg2     = (int*)w; w += NNODES;
    int* offsets2 = (int*)w; w += NNODES + 1;
    int* cursor2  = (int*)w; w += NNODES;
    int* partial  = (int*)w; w += 512;
    int* csr_e  = (int*)w; w += M;
    int* csr_te = (int*)w; w += M;
    int* csr_er = (int*)w; w += M;
    int* csr_tn = (int*)w; w += M;
    int* csr_bi = (int*)w; w += M;
    int* hcsr_hn = (int*)w; w += M;
    int* hcsr_er = (int*)w; w += M;
    int* hcsr_qr = (int*)w; w += M;
    int* hcsr_e  = (int*)w; w += M;
    w = (float*)(((uintptr_t)w + 63) & ~(uintptr_t)63);
    // BIG region: phase 2-3: nodeWs16 (51.2 MB); phase 6-7: gx16|gh16 (76.8 MB)
    float* big = w;
    ushort* nodeWs16 = (ushort*)big;
    ushort* gx16 = (ushort*)big;
    ushort* gh16 = (ushort*)big + (size_t)NC * 768;

    // (0) CSR builds (fused histogram; permuted attribute arrays)
    hipMemsetAsync(deg, 0, NNEW * sizeof(int), stream);
    hipMemsetAsync(deg2, 0, NNODES * sizeof(int), stream);
    hist2_k<<<(M + 255) / 256, 256, 0, stream>>>(tail_node, head_node, deg, deg2, M);
    scan1_k<<<NP_T, 512, 0, stream>>>(deg, partial, NNEW);
    scan2_k<<<1, 256, 0, stream>>>(partial, NP_T, offsets, NNEW, M);
    scan3_k<<<NP_T, 512, 0, stream>>>(deg, partial, offsets, cursor, NNEW);
    fill_k<<<(M + 255) / 256, 256, 0, stream>>>(tail_node, tail_ent, edge_rel,
        batch_idx, cursor, csr_e, csr_te, csr_er, csr_tn, csr_bi, M);
    scan1_k<<<NP_H, 512, 0, stream>>>(deg2, partial, NNODES);
    scan2_k<<<1, 256, 0, stream>>>(partial, NP_H, offsets2, NNODES, M);
    scan3_k<<<NP_H, 512, 0, stream>>>(deg2, partial, offsets2, cursor2, NNODES);
    hfill_k<<<(M + 255) / 256, 256, 0, stream>>>(head_node, edge_rel, query_rel,
        cursor2, hcsr_hn, hcsr_er, hcsr_qr, hcsr_e, M);

    // (1) weight prep + tables + qdot
    convert16_k<<<(NENT * E + 255) / 256, 256, 0, stream>>>(entity_emb, ent16, NENT * E);
    convertW_k<<<1536, 256, 0, stream>>>(W_ih, W_hh, W_ih16, W_hh16);
    transpose4_k<<<dim3(256, 4), 256, 0, stream>>>(
        Ws, We2h_W, cand_W, WsT16, We2hT16, candW1T16, candW3T16);
    relprep_k<<<dim3(8, 4, 3), 256, 0, stream>>>(
        relation_emb, Wr, Wqr, cand_W + 128 * 256,
        relWr, relWqr, relCand16, NREL, 256, 128);
    qdot_k<<<64, 256, 0, stream>>>(query_repr, rank_W, qdot);

    // (2) nodeWs16 = bf16(node_hidden @ Ws)   [64x256 block, A read once]
    gemm16pw_k<<<(NNODES + 63) / 64, 256, 0, stream>>>(
        node_hidden, WsT16, nullptr, nodeWs16, NNODES, 256, ACT_NONE);

    // (3) alpha (head-sorted)
    alpha_k<<<M / 32, 256, 0, stream>>>(nodeWs16, relWr, relWqr, bqr, w_alpha, b_alpha,
                                        hcsr_hn, hcsr_er, hcsr_qr, hcsr_e, alpha);

    // (4) segment sum via CSR
    agg_csr_k<<<NNEW / 4, 256, 0, stream>>>(relation_emb, ent16, alpha,
                                            csr_e, csr_er, csr_te, offsets, agg16);

    // (5) h_prev16 = bf16(lrelu(ent16[tail_node_ent] @ We2h_W + We2h_b))
    gemm16p_k<<<dim3(2, (NNEW + 127) / 128), 256, 0, stream>>>(
        ent16, tail_node_ent, We2hT16, We2h_b, nullptr, h_prev16, NNEW, 256, 128, ACT_LRELU);

    // (6,7,8) GRU chunks: gx/gh GEMMs + fused GRU/LN/candW3
    for (int ch = 0; ch < NCHUNK; ++ch) {
        int n0 = ch * NC;
        gemm16p_k<<<dim3(6, (NC + 127) / 128), 256, 0, stream>>>(
            agg16 + (size_t)n0 * 256, nullptr, W_ih16, b_ih, nullptr, gx16, NC, 768, 256, ACT_NONE);
        gemm16p_k<<<dim3(6, (NC + 127) / 128), 256, 0, stream>>>(
            h_prev16 + (size_t)n0 * 256, nullptr, W_hh16, b_hh, nullptr, gh16, NC, 768, 256, ACT_NONE);
        gruln_cand_k<<<(NC + 63) / 64, 256, 0, stream>>>(
            gx16, gh16, h_prev16, ln_g, ln_b, cand_b, candW3T16, hnewCand16, n0, NC);
    }

    // (9) fused score (64 edges/block, CSR order)
    score_mfma_k<<<M / 64, 256, 0, stream>>>(
        ent16, candW1T16, relCand16, hnewCand16, rank_W, rank_b, qdot,
        csr_e, csr_te, csr_er, csr_tn, csr_bi, out);
}